// Round 5
// baseline (10418.560 us; speedup 1.0000x reference)
//
#include <hip/hip_runtime.h>

// ============================================================================
// R12: batch-split pipelining of the critical L1<->ATT cycle (R11 + split).
//  - 64 batches -> two groups (rows 0-31 "A", 32-63 "B") offset a half-step.
//    L1: phase A (recurrent ks2-14, full 64) unchanged; then per group:
//    wait ATT_g(t-1) -> w-MFMA (2 m-tiles) -> finish(32 rows) -> arrive L1g(t).
//    ATT WGs 0-7 key off L1A, 8-15 off L1B. ATT_A's hop+compute hides behind
//    L1's B-half + next phase A (and symmetrically).
//  - Program order: L1B(t) implies L1A(t) done -> L2/L3/OUT wait L1B only.
//  - Flag protocol, p-partials, self-staged x: unchanged from R11.
// Label: "R12 batch-split L1/ATT pipeline"
// ============================================================================

#define DI __device__ __forceinline__

typedef _Float16 f16;
typedef _Float16 f16x8 __attribute__((ext_vector_type(8)));
typedef _Float16 f16x4 __attribute__((ext_vector_type(4)));
typedef float f32x4 __attribute__((ext_vector_type(4)));
typedef unsigned long long u64;
typedef unsigned u32;

constexpr int Tn = 800, Un = 96, Hn = 400;
constexpr int P1 = 520, P2 = 904, P3 = 904, PM = 1288;
constexpr int NWG = 99;
constexpr int SP = 272;  // LDS staging pitch (f16)

constexpr size_t OFF_W1 = 0;
constexpr size_t SZ_W1 = (size_t)1600 * P1 * 2;
constexpr size_t OFF_W2 = OFF_W1 + SZ_W1;
constexpr size_t SZ_W2 = (size_t)1600 * P2 * 2;
constexpr size_t OFF_W3 = OFF_W2 + SZ_W2;
constexpr size_t OFF_WM = OFF_W3 + SZ_W2;
constexpr size_t SZ_WM = (size_t)128 * PM * 2;
constexpr size_t OFF_A1 = OFF_WM + SZ_WM;
constexpr size_t SZ_A1 = (size_t)2 * 64 * P1 * 2;
constexpr size_t OFF_A2 = OFF_A1 + SZ_A1;
constexpr size_t SZ_A2 = (size_t)2 * 64 * P2 * 2;
constexpr size_t OFF_A3 = OFF_A2 + SZ_A2;
constexpr size_t OFF_AM = OFF_A3 + SZ_A2;
constexpr size_t SZ_AM = (size_t)4 * 64 * PM * 2;   // quad-buffered (OUT lag)
constexpr size_t OFF_TEB = OFF_AM + SZ_AM;
constexpr size_t SZ_TEB = (size_t)64 * 96 * 64 * 2;
constexpr size_t OFF_BS1 = OFF_TEB + SZ_TEB;
constexpr size_t OFF_BS2 = OFF_BS1 + 6400;
constexpr size_t OFF_BS3 = OFF_BS2 + 6400;
constexpr size_t OFF_BW = OFF_BS3 + 6400;
constexpr size_t OFF_BM = OFF_BW + 128;
constexpr size_t OFF_FLG = OFF_BM + 512;
constexpr size_t SZ_FLG = (size_t)808 * 5 * 16 * 4;  // region reused: flags + PB
constexpr size_t OFF_PB = OFF_FLG + 4096;            // 25*64*32 f32 = 204800 B
constexpr size_t OFF_RES = OFF_FLG + SZ_FLG;

constexpr size_t O_EOS = 0, O_PI = 51200, O_MUX = 1075200, O_MUY = 2099200;
constexpr size_t O_SX = 3123200, O_SY = 4147200, O_RHO = 5171200;

// slot bases: one int per (role, wg)
constexpr int SB_L1 = 0;      // 25 slots (L1 group A, rows 0-31)
constexpr int SB_ATT = 32;    // 16 slots (0-7 group A, 8-15 group B)
constexpr int SB_L2 = 64;     // 25 slots
constexpr int SB_L3 = 96;     // 25 slots
constexpr int SB_OUT = 128;   // 8 slots
constexpr int SB_L1B = 160;   // 25 slots (L1 group B, rows 32-63)
constexpr int NSLOT = 192;

constexpr int GUARD_FLAG = 1200000;

// ---- sc1 LLC data movers ----
DI u64 ldU8(const f16* p) {
  return __hip_atomic_load((const u64*)p, __ATOMIC_RELAXED, __HIP_MEMORY_SCOPE_AGENT);
}
DI void stU8(f16* p, u64 u) {
  __hip_atomic_store((u64*)p, u, __ATOMIC_RELAXED, __HIP_MEMORY_SCOPE_AGENT);
}
DI void stU8u(void* p, u64 u) {
  __hip_atomic_store((u64*)p, u, __ATOMIC_RELAXED, __HIP_MEMORY_SCOPE_AGENT);
}
DI u32 ldU4(const u32* p) {
  return __hip_atomic_load(p, __ATOMIC_RELAXED, __HIP_MEMORY_SCOPE_AGENT);
}
DI void stA4(f16* p, f16x4 v) {
  union { f16x4 v; u64 u; } c; c.v = v;
  stU8(p, c.u);
}
DI u64 pkf(float a, float b) {
  return (u64)__builtin_bit_cast(u32, a) | ((u64)__builtin_bit_cast(u32, b) << 32);
}

// ---- slot wait: up to 4 ranges of (base, count, t_required) ----
DI void waitR(int* sl, int* doom,
              int b0, int n0, int q0, int b1, int n1, int q1,
              int b2, int n2, int q2, int b3, int n3, int q3) {
  if (!*doom) {
    if (threadIdx.x < 64) {
      const int l = (int)threadIdx.x;
      int sA = -1, qA = 0, sB = -1, qB = 0;
      {
        int idx = l;
        if (idx < n0) { sA = b0 + idx; qA = q0; }
        else { idx -= n0;
          if (idx < n1) { sA = b1 + idx; qA = q1; }
          else { idx -= n1;
            if (idx < n2) { sA = b2 + idx; qA = q2; }
            else { idx -= n2;
              if (idx < n3) { sA = b3 + idx; qA = q3; } } } }
      }
      {
        int idx = l + 64;
        if (idx < n0) { sB = b0 + idx; qB = q0; }
        else { idx -= n0;
          if (idx < n1) { sB = b1 + idx; qB = q1; }
          else { idx -= n1;
            if (idx < n2) { sB = b2 + idx; qB = q2; }
            else { idx -= n2;
              if (idx < n3) { sB = b3 + idx; qB = q3; } } } }
      }
      int okA = (sA < 0) ? 1 : 0, okB = (sB < 0) ? 1 : 0;
      int guard = 0;
      for (;;) {
        if (!okA)
          okA = (__hip_atomic_load(sl + sA, __ATOMIC_RELAXED, __HIP_MEMORY_SCOPE_AGENT) >= qA) ? 1 : 0;
        if (!okB)
          okB = (__hip_atomic_load(sl + sB, __ATOMIC_RELAXED, __HIP_MEMORY_SCOPE_AGENT) >= qB) ? 1 : 0;
        if (__all(okA & okB)) break;
        __builtin_amdgcn_s_sleep(1);
        if (++guard > GUARD_FLAG) { if (l == 0) *doom = 1; break; }  // fail visible
      }
    }
  }
  __syncthreads();
}
// ---- arrive: syncthreads drains all waves' sc1 stores before the slot store
DI void arriveS(int* sl, int slot, int t) {
  __syncthreads();
  if (threadIdx.x == 0)
    __hip_atomic_store(sl + slot, t, __ATOMIC_RELAXED, __HIP_MEMORY_SCOPE_AGENT);
}

DI float sigm(float v) { return 1.f / (1.f + expf(-v)); }

// ---- staging split: issue all loads first, write LDS later ----
template <int KN, int PITCH_>
DI void stage_ld(const f16* Ain, int tid, u64* lo, u64* hi) {
#pragma unroll
  for (int j = 0; j < KN; ++j) {
    const int i = tid + j * 256;
    const int r = i / (KN * 4), c16 = i % (KN * 4);
    const f16* p = Ain + (size_t)r * PITCH_ + c16 * 8;
    lo[j] = ldU8(p);
    hi[j] = ldU8(p + 4);
  }
}
template <int KN>
DI void stage_wr(f16* stg, int tid, const u64* lo, const u64* hi) {
#pragma unroll
  for (int j = 0; j < KN; ++j) {
    const int i = tid + j * 256;
    const int r = i / (KN * 4), c16 = i % (KN * 4);
    u64* q = (u64*)(stg + r * SP + c16 * 8);
    q[0] = lo[j];
    q[1] = hi[j];
  }
}
template <int KN>
DI void mfma_blk(const f16x8* wr, const f16* stg, int quad, int ln16, f32x4 acc[4]) {
#pragma unroll
  for (int ksl = 0; ksl < KN; ++ksl) {
    const int kc = ksl * 32 + quad * 8;
#pragma unroll
    for (int mt = 0; mt < 4; ++mt) {
      const f16x8 a = *(const f16x8*)(stg + (mt * 16 + ln16) * SP + kc);
      acc[mt] = __builtin_amdgcn_mfma_f32_16x16x32_f16(a, wr[ksl], acc[mt], 0, 0, 0);
    }
  }
}

// ---- half-group (32-row) w staging + 2-kstep MFMA on 2 m-tiles ----
DI void stage_wHalf_ld(const f16* Ap, int pitch, int half, int tid, u64& lo, u64& hi) {
  const int r = tid >> 3, c8 = (tid & 7) * 8;
  const f16* p = Ap + (size_t)(half * 32 + r) * pitch + c8;
  lo = ldU8(p);
  hi = ldU8(p + 4);
}
DI void stage_wHalf_wr(f16* stg, int tid, u64 lo, u64 hi) {
  const int r = tid >> 3, c8 = (tid & 7) * 8;
  u64* q = (u64*)(stg + r * SP + c8);
  q[0] = lo;
  q[1] = hi;
}
DI void mfma_blkH2(const f16x8* wr, const f16* stg, int quad, int ln16, f32x4* accH) {
#pragma unroll
  for (int ksl = 0; ksl < 2; ++ksl) {
    const int kc = ksl * 32 + quad * 8;
#pragma unroll
    for (int mtl = 0; mtl < 2; ++mtl) {
      const f16x8 a = *(const f16x8*)(stg + (mtl * 16 + ln16) * SP + kc);
      accH[mtl] = __builtin_amdgcn_mfma_f32_16x16x32_f16(a, wr[ksl], accH[mtl], 0, 0, 0);
    }
  }
}

// ---- ks14 staging: A cols 448..463 + x(t) direct from global (full 64) ----
DI void stage_ks14_ld(const f16* Ap, int pitch, const float* x, int t, int tid,
                      u64& sp, float& x0, float& x1, float& x2) {
  const int r = tid >> 2, cc = (tid & 3) * 4;
  sp = ldU8(Ap + (size_t)r * pitch + 448 + cc);
  if (tid < 64) {
    const float* xp = x + ((size_t)tid * Tn + t) * 3;
    x0 = xp[0]; x1 = xp[1]; x2 = xp[2];
  } else { x0 = x1 = x2 = 0.f; }
}
DI void stage_ks14_wr(f16* stg, int tid, u64 sp, float x0, float x1, float x2) {
  const int r = tid >> 2, cc = (tid & 3) * 4;
  *(u64*)(stg + r * SP + 128 + cc) = sp;         // LDS cols 128..143
  if (tid < 64) {
    union { f16 h[4]; u64 u; } cx;
    cx.h[0] = (f16)x0; cx.h[1] = (f16)x1; cx.h[2] = (f16)x2; cx.h[3] = (f16)0.f;
    *(u64*)(stg + tid * SP + 144) = cx.u;        // LDS cols 144..147
    *(u64*)(stg + tid * SP + 148) = 0ull;        // cols 148..159 zeroed
    *(u64*)(stg + tid * SP + 152) = 0ull;
    *(u64*)(stg + tid * SP + 156) = 0ull;
  }
}

// ---- gate finish (L2/L3): cross-wave reduce + LSTM nonlin + h stores ----
DI void gate_finish(f32x4 acc[4], float* red, float* cst, const float* bL, int tid,
                    int quad, int ln16, int wave,
                    f16* dA, int pA, f16* dB, int pB, f16* dC, int pC) {
#pragma unroll
  for (int mt = 0; mt < 4; ++mt)
#pragma unroll
    for (int r = 0; r < 4; ++r)
      red[wave * 1024 + (mt * 16 + quad * 4 + r) * 16 + ln16] = acc[mt][r];
  __syncthreads();
  {
    const int oi = tid * 4, b = oi >> 4, j0 = oi & 15;
    f32x4 gi = *(f32x4*)&red[oi];
    f32x4 gf = *(f32x4*)&red[1024 + oi];
    f32x4 gg = *(f32x4*)&red[2048 + oi];
    f32x4 go = *(f32x4*)&red[3072 + oi];
    f32x4 c = *(f32x4*)&cst[oi];
    f16x4 hv;
#pragma unroll
    for (int e = 0; e < 4; ++e) {
      const float iv = sigm(gi[e] + bL[j0 + e]);
      const float fv = sigm(gf[e] + bL[16 + j0 + e]);
      const float gv = tanhf(gg[e] + bL[32 + j0 + e]);
      const float ov = sigm(go[e] + bL[48 + j0 + e]);
      const float cn = fv * c[e] + iv * gv;
      c[e] = cn;
      hv[e] = (f16)(ov * tanhf(cn));
    }
    *(f32x4*)&cst[oi] = c;
    stA4(dA + b * pA + j0, hv);
    stA4(dB + b * pB + j0, hv);
    if (dC != nullptr) stA4(dC + b * pC + j0, hv);
  }
}

// ---- L1 half-group finish: 32 rows (2 m-tiles), nonlin + p-partial + h ----
// dA/dB/dC pre-offset by half*32*pitch. PB row = jb*64 + half*32 + b.
DI void gate_finish_l1h(f32x4* accH, int half, float* red, float* cst,
                        const float* bL, const float* wwL, int tid, int quad,
                        int ln16, int wave, u32* PBu, int jb,
                        f16* dA, int pA, f16* dB, int pB, f16* dC, int pC) {
#pragma unroll
  for (int mtl = 0; mtl < 2; ++mtl)
#pragma unroll
    for (int r = 0; r < 4; ++r)
      red[wave * 512 + (mtl * 16 + quad * 4 + r) * 16 + ln16] = accH[mtl][r];
  __syncthreads();
  if (tid < 128) {
    const int oi = tid * 4, b = oi >> 4, j0 = oi & 15;  // b in [0,32)
    f32x4 gi = *(f32x4*)&red[oi];
    f32x4 gf = *(f32x4*)&red[512 + oi];
    f32x4 gg = *(f32x4*)&red[1024 + oi];
    f32x4 go = *(f32x4*)&red[1536 + oi];
    f32x4 c = *(f32x4*)&cst[half * 512 + oi];
    float hq[4];
    f16x4 hv;
#pragma unroll
    for (int e = 0; e < 4; ++e) {
      const float iv = sigm(gi[e] + bL[j0 + e]);
      const float fv = sigm(gf[e] + bL[16 + j0 + e]);
      const float gv = tanhf(gg[e] + bL[32 + j0 + e]);
      const float ov = sigm(go[e] + bL[48 + j0 + e]);
      const float cn = fv * c[e] + iv * gv;
      c[e] = cn;
      hq[e] = ov * tanhf(cn);
      hv[e] = (f16)hq[e];
    }
    *(f32x4*)&cst[half * 512 + oi] = c;
    // p-partial over this WG's 16 H-cols (f32); shfl within 4-lane group
    float p[30];
#pragma unroll
    for (int r = 0; r < 30; ++r) {
      const f32x4 wv = *(const f32x4*)&wwL[r * 16 + j0];
      p[r] = wv[0] * hq[0] + wv[1] * hq[1] + wv[2] * hq[2] + wv[3] * hq[3];
    }
#pragma unroll
    for (int r = 0; r < 30; ++r) {
      p[r] += __shfl_xor(p[r], 1);
      p[r] += __shfl_xor(p[r], 2);
    }
    {
      const int s4 = tid & 3;
      u64* drow = (u64*)(PBu + (size_t)(jb * 64 + half * 32 + b) * 32);
      if (s4 == 0) {
        stU8u(drow + 0, pkf(p[0], p[1]));   stU8u(drow + 1, pkf(p[2], p[3]));
        stU8u(drow + 2, pkf(p[4], p[5]));   stU8u(drow + 3, pkf(p[6], p[7]));
      } else if (s4 == 1) {
        stU8u(drow + 4, pkf(p[8], p[9]));   stU8u(drow + 5, pkf(p[10], p[11]));
        stU8u(drow + 6, pkf(p[12], p[13])); stU8u(drow + 7, pkf(p[14], p[15]));
      } else if (s4 == 2) {
        stU8u(drow + 8, pkf(p[16], p[17])); stU8u(drow + 9, pkf(p[18], p[19]));
        stU8u(drow + 10, pkf(p[20], p[21])); stU8u(drow + 11, pkf(p[22], p[23]));
      } else {
        stU8u(drow + 12, pkf(p[24], p[25])); stU8u(drow + 13, pkf(p[26], p[27]));
        stU8u(drow + 14, pkf(p[28], p[29]));
      }
    }
    stA4(dA + b * pA + j0, hv);
    stA4(dB + b * pB + j0, hv);
    if (dC != nullptr) stA4(dC + b * pC + j0, hv);
  }
}

// ---- L1 role (25 WGs) ----
DI void l1_role(char* ws, char* smem, int jb, const float* x, const float* Ww) {
  const int tid = threadIdx.x;
  const int wave = tid >> 6, lane = tid & 63, ln16 = lane & 15, quad = lane >> 4;
  const f16* W1 = (const f16*)(ws + OFF_W1);
  f16* A1 = (f16*)(ws + OFF_A1);
  f16* A2 = (f16*)(ws + OFF_A2);
  f16* AM = (f16*)(ws + OFF_AM);
  int* sl = (int*)(ws + OFF_FLG);
  u32* PBu = (u32*)(ws + OFF_PB);
  f16* stg = (f16*)smem;                    // 34816
  float* red = (float*)(smem + 34816);      // 16384
  float* cst = (float*)(smem + 51200);      // 4096
  float* bL = (float*)(smem + 55296);       // 256
  float* wwL = (float*)(smem + 55552);      // 1920 ([30][16] Ww slice)
  int* doom = (int*)(smem + 59384);
  const int row = wave * Hn + jb * 16 + ln16;
  f16x8 wr[16];
#pragma unroll
  for (int i = 0; i < 16; ++i) wr[i] = *(const f16x8*)(W1 + (size_t)row * P1 + i * 32 + quad * 8);
  if (tid < 64) bL[tid] = ((const float*)(ws + OFF_BS1))[(tid >> 4) * Hn + jb * 16 + (tid & 15)];
  for (int i = tid; i < 480; i += 256) {
    const int rr = i >> 4, jj = i & 15;
    wwL[i] = Ww[rr * 400 + jb * 16 + jj];
  }
  for (int z = tid; z < 1024; z += 256) cst[z] = 0.f;
  if (tid == 0) *doom = 0;
  __syncthreads();
  for (int t = 0; t < Tn; ++t) {
    const f16* Ap = A1 + (size_t)(t & 1) * 64 * P1;
    f16* A1n = A1 + (size_t)((t + 1) & 1) * 64 * P1;
    f16* A2c = A2 + (size_t)(t & 1) * 64 * P2;
    f16* AMc = AM + (size_t)(t & 3) * 64 * PM;
    f32x4 acc[4];
#pragma unroll
    for (int mt = 0; mt < 4; ++mt) acc[mt] = f32x4{0.f, 0.f, 0.f, 0.f};
    // phase A: h1-rec ks2..14 + x, full 64 rows (needs L1B(t-1) => both halves)
    waitR(sl, doom, SB_L1B, 25, t - 1, SB_L2, 25, t - 2, SB_OUT, 8, t - 4, 0, 0, 0);
    {
      u64 lo8[8], hi8[8], lo4[4], hi4[4], sp;
      float x0, x1, x2;
      stage_ld<8, P1>(Ap + 2 * 32, tid, lo8, hi8);
      stage_ld<4, P1>(Ap + 10 * 32, tid, lo4, hi4);
      stage_ks14_ld(Ap, P1, x, t, tid, sp, x0, x1, x2);
      stage_wr<8>(stg, tid, lo8, hi8);
      __syncthreads();
      mfma_blk<8>(wr + 2, stg, quad, ln16, acc);
      __syncthreads();
      stage_wr<4>(stg, tid, lo4, hi4);
      stage_ks14_wr(stg, tid, sp, x0, x1, x2);
      __syncthreads();
      mfma_blk<4>(wr + 10, stg, quad, ln16, acc);
      mfma_blk<1>(wr + 14, stg + 128, quad, ln16, acc);
      // ks15 = pure zero padding: skipped
    }
    // ---- A half (rows 0-31): w(t-1) from ATT group A ----
    waitR(sl, doom, SB_ATT, 8, t - 1, 0, 0, 0, 0, 0, 0, 0, 0, 0);
    {
      u64 lo, hi;
      stage_wHalf_ld(Ap, P1, 0, tid, lo, hi);
      stage_wHalf_wr(stg, tid, lo, hi);
      __syncthreads();
      mfma_blkH2(wr + 0, stg, quad, ln16, &acc[0]);
    }
    gate_finish_l1h(&acc[0], 0, red, cst, bL, wwL, tid, quad, ln16, wave, PBu, jb,
                    A1n + 64 + jb * 16, P1,
                    A2c + 64 + jb * 16, P2,
                    AMc + jb * 16, PM);
    arriveS(sl, SB_L1 + jb, t);
    // ---- B half (rows 32-63): w(t-1) from ATT group B ----
    waitR(sl, doom, SB_ATT + 8, 8, t - 1, 0, 0, 0, 0, 0, 0, 0, 0, 0);
    {
      u64 lo, hi;
      stage_wHalf_ld(Ap, P1, 1, tid, lo, hi);
      stage_wHalf_wr(stg, tid, lo, hi);
      __syncthreads();
      mfma_blkH2(wr + 0, stg, quad, ln16, &acc[2]);
    }
    gate_finish_l1h(&acc[2], 1, red, cst, bL, wwL, tid, quad, ln16, wave, PBu, jb,
                    A1n + (size_t)32 * P1 + 64 + jb * 16, P1,
                    A2c + (size_t)32 * P2 + 64 + jb * 16, P2,
                    AMc + (size_t)32 * PM + jb * 16, PM);
    arriveS(sl, SB_L1B + jb, t);
  }
}

// ---- L2 role (25 WGs) ----
DI void l2_role(char* ws, char* smem, int jb, const float* x) {
  const int tid = threadIdx.x;
  const int wave = tid >> 6, lane = tid & 63, ln16 = lane & 15, quad = lane >> 4;
  const f16* W2 = (const f16*)(ws + OFF_W2);
  f16* A2 = (f16*)(ws + OFF_A2);
  f16* A3 = (f16*)(ws + OFF_A3);
  f16* AM = (f16*)(ws + OFF_AM);
  int* sl = (int*)(ws + OFF_FLG);
  f16* stg = (f16*)smem;
  float* red = (float*)(smem + 34816);
  float* cst = (float*)(smem + 51200);
  float* bL = (float*)(smem + 55296);
  int* doom = (int*)(smem + 59384);
  const int row = wave * Hn + jb * 16 + ln16;
  f16x8 wr[28];
#pragma unroll
  for (int i = 0; i < 28; ++i) wr[i] = *(const f16x8*)(W2 + (size_t)row * P2 + i * 32 + quad * 8);
  if (tid < 64) bL[tid] = ((const float*)(ws + OFF_BS2))[(tid >> 4) * Hn + jb * 16 + (tid & 15)];
  for (int z = tid; z < 1024; z += 256) cst[z] = 0.f;
  if (tid == 0) *doom = 0;
  __syncthreads();
  for (int t = 0; t < Tn; ++t) {
    const f16* Ap = A2 + (size_t)(t & 1) * 64 * P2;
    f32x4 acc[4];
#pragma unroll
    for (int mt = 0; mt < 4; ++mt) acc[mt] = f32x4{0.f, 0.f, 0.f, 0.f};
    // phase A: h2-rec ks15..27 (own t-1); WAR: A3 h2-slot (L3), AM (OUT)
    waitR(sl, doom, SB_L2, 25, t - 1, SB_L3, 25, t - 2, SB_OUT, 8, t - 4, 0, 0, 0);
    {
      u64 lo8[8], hi8[8], lo5[5], hi5[5];
      stage_ld<8, P2>(Ap + 15 * 32, tid, lo8, hi8);
      stage_ld<5, P2>(Ap + 23 * 32, tid, lo5, hi5);
      stage_wr<8>(stg, tid, lo8, hi8);
      __syncthreads();
      mfma_blk<8>(wr + 15, stg, quad, ln16, acc);
      __syncthreads();
      stage_wr<5>(stg, tid, lo5, hi5);
      __syncthreads();
      mfma_blk<5>(wr + 23, stg, quad, ln16, acc);
    }
    // phase B: h1(t) + x ks2..14 (needs L1B(t) => both halves)
    waitR(sl, doom, SB_L1B, 25, t, 0, 0, 0, 0, 0, 0, 0, 0, 0);
    {
      u64 lo8[8], hi8[8], lo4[4], hi4[4], sp;
      float x0, x1, x2;
      stage_ld<8, P2>(Ap + 2 * 32, tid, lo8, hi8);
      stage_ld<4, P2>(Ap + 10 * 32, tid, lo4, hi4);
      stage_ks14_ld(Ap, P2, x, t, tid, sp, x0, x1, x2);
      stage_wr<8>(stg, tid, lo8, hi8);
      __syncthreads();
      mfma_blk<8>(wr + 2, stg, quad, ln16, acc);
      __syncthreads();
      stage_wr<4>(stg, tid, lo4, hi4);
      stage_ks14_wr(stg, tid, sp, x0, x1, x2);
      __syncthreads();
      mfma_blk<4>(wr + 10, stg, quad, ln16, acc);
      mfma_blk<1>(wr + 14, stg + 128, quad, ln16, acc);
    }
    // phase C: w(t) (needs all ATT(t)) -> ks0..1
    waitR(sl, doom, SB_ATT, 16, t, 0, 0, 0, 0, 0, 0, 0, 0, 0);
    {
      u64 lo2[2], hi2[2];
      stage_ld<2, P2>(Ap + 0, tid, lo2, hi2);
      stage_wr<2>(stg, tid, lo2, hi2);
      __syncthreads();
      mfma_blk<2>(wr + 0, stg, quad, ln16, acc);
    }
    gate_finish(acc, red, cst, bL, tid, quad, ln16, wave,
                A2 + (size_t)((t + 1) & 1) * 64 * P2 + 480 + jb * 16, P2,
                A3 + (size_t)(t & 1) * 64 * P3 + 64 + jb * 16, P3,
                AM + (size_t)(t & 3) * 64 * PM + Hn + jb * 16, PM);
    arriveS(sl, SB_L2 + jb, t);
  }
}

// ---- L3 role (25 WGs) ----
DI void l3_role(char* ws, char* smem, int jb, const float* x) {
  const int tid = threadIdx.x;
  const int wave = tid >> 6, lane = tid & 63, ln16 = lane & 15, quad = lane >> 4;
  const f16* W3 = (const f16*)(ws + OFF_W3);
  f16* A3 = (f16*)(ws + OFF_A3);
  f16* AM = (f16*)(ws + OFF_AM);
  int* sl = (int*)(ws + OFF_FLG);
  f16* stg = (f16*)smem;
  float* red = (float*)(smem + 34816);
  float* cst = (float*)(smem + 51200);
  float* bL = (float*)(smem + 55296);
  int* doom = (int*)(smem + 59384);
  const int row = wave * Hn + jb * 16 + ln16;
  f16x8 wr[28];
#pragma unroll
  for (int i = 0; i < 28; ++i) wr[i] = *(const f16x8*)(W3 + (size_t)row * P3 + i * 32 + quad * 8);
  if (tid < 64) bL[tid] = ((const float*)(ws + OFF_BS3))[(tid >> 4) * Hn + jb * 16 + (tid & 15)];
  for (int z = tid; z < 1024; z += 256) cst[z] = 0.f;
  if (tid == 0) *doom = 0;
  __syncthreads();
  for (int t = 0; t < Tn; ++t) {
    const f16* Ap = A3 + (size_t)(t & 1) * 64 * P3;
    f32x4 acc[4];
#pragma unroll
    for (int mt = 0; mt < 4; ++mt) acc[mt] = f32x4{0.f, 0.f, 0.f, 0.f};
    // phase A: h3-rec ks15..27 (own t-1); WAR: AM (OUT)
    waitR(sl, doom, SB_L3, 25, t - 1, SB_OUT, 8, t - 4, 0, 0, 0, 0, 0, 0);
    {
      u64 lo8[8], hi8[8], lo5[5], hi5[5];
      stage_ld<8, P3>(Ap + 15 * 32, tid, lo8, hi8);
      stage_ld<5, P3>(Ap + 23 * 32, tid, lo5, hi5);
      stage_wr<8>(stg, tid, lo8, hi8);
      __syncthreads();
      mfma_blk<8>(wr + 15, stg, quad, ln16, acc);
      __syncthreads();
      stage_wr<5>(stg, tid, lo5, hi5);
      __syncthreads();
      mfma_blk<5>(wr + 23, stg, quad, ln16, acc);
    }
    // phase B: h2(t) + x ks2..14 (needs L2(t))
    waitR(sl, doom, SB_L2, 25, t, 0, 0, 0, 0, 0, 0, 0, 0, 0);
    {
      u64 lo8[8], hi8[8], lo4[4], hi4[4], sp;
      float x0, x1, x2;
      stage_ld<8, P3>(Ap + 2 * 32, tid, lo8, hi8);
      stage_ld<4, P3>(Ap + 10 * 32, tid, lo4, hi4);
      stage_ks14_ld(Ap, P3, x, t, tid, sp, x0, x1, x2);
      stage_wr<8>(stg, tid, lo8, hi8);
      __syncthreads();
      mfma_blk<8>(wr + 2, stg, quad, ln16, acc);
      __syncthreads();
      stage_wr<4>(stg, tid, lo4, hi4);
      stage_ks14_wr(stg, tid, sp, x0, x1, x2);
      __syncthreads();
      mfma_blk<4>(wr + 10, stg, quad, ln16, acc);
      mfma_blk<1>(wr + 14, stg + 128, quad, ln16, acc);
    }
    // phase C: w(t) (needs all ATT(t)) -> ks0..1
    waitR(sl, doom, SB_ATT, 16, t, 0, 0, 0, 0, 0, 0, 0, 0, 0);
    {
      u64 lo2[2], hi2[2];
      stage_ld<2, P3>(Ap + 0, tid, lo2, hi2);
      stage_wr<2>(stg, tid, lo2, hi2);
      __syncthreads();
      mfma_blk<2>(wr + 0, stg, quad, ln16, acc);
    }
    gate_finish(acc, red, cst, bL, tid, quad, ln16, wave,
                A3 + (size_t)((t + 1) & 1) * 64 * P3 + 480 + jb * 16, P3,
                AM + (size_t)(t & 3) * 64 * PM + 2 * Hn + jb * 16, PM,
                nullptr, 0);
    arriveS(sl, SB_L3 + jb, t);
  }
}

// ---- attention role (16 WGs x 4 batches; ab<8 group A, ab>=8 group B) ----
DI void att_role(char* ws, char* smem, int ab) {
  const int tid = threadIdx.x;
  const int b0 = ab * 4;
  const int grp = ab >> 3;                 // 0: batches 0-31, 1: 32-63
  const int sbL1g = grp ? SB_L1B : SB_L1;
  f16* A1 = (f16*)(ws + OFF_A1);
  f16* A2 = (f16*)(ws + OFF_A2);
  f16* A3 = (f16*)(ws + OFF_A3);
  int* sl = (int*)(ws + OFF_FLG);
  const u32* PBu = (const u32*)(ws + OFF_PB);
  f16* tebL = (f16*)smem;                 // 49152
  float* aL = (float*)(smem + 49152);     // 160
  float* beL = (float*)(smem + 49312);    // 160
  float* kaL = (float*)(smem + 49472);    // 160 (persistent kappa)
  float* phiL = (float*)(smem + 49632);   // 1536
  float* bwL = (float*)(smem + 51168);    // 120
  f16* wL = (f16*)(smem + 51296);         // 512
  int* doom = (int*)(smem + 59384);
  for (int i = tid; i < 24576; i += 256)
    tebL[i] = ((const f16*)(ws + OFF_TEB))[(size_t)b0 * 6144 + i];
  if (tid < 40) kaL[tid] = 0.f;
  if (tid < 30) bwL[tid] = ((const float*)(ws + OFF_BW))[tid];
  if (tid == 0) *doom = 0;
  __syncthreads();
  const int bl = tid / 30, r = tid % 30;
  const bool act = tid < 120;
  const u32* pbase = PBu + (size_t)(b0 + (act ? bl : 0)) * 32 + (act ? r : 0);
  for (int t = 0; t < Tn; ++t) {
    // needs own group's L1 p-partials; WAR: w slots in A2/A3 (L2/L3 at t-2)
    waitR(sl, doom, sbL1g, 25, t, SB_L2, 25, t - 2, SB_L3, 25, t - 2, 0, 0, 0);
    if (act) {
      float s = bwL[r];
#pragma unroll
      for (int jb = 0; jb < 25; ++jb)
        s += __builtin_bit_cast(float, ldU4(pbase + jb * 2048));
      if (r < 10) aL[bl * 10 + r] = expf(s);
      else if (r < 20) beL[bl * 10 + r - 10] = expf(s);
      else kaL[bl * 10 + r - 20] += expf(fminf(5.f, fmaxf(-10.f, s)));
    }
    __syncthreads();
    for (int idx = tid; idx < 384; idx += 256) {
      const int b = idx / 96;
      const float u1 = (float)(idx % 96 + 1);
      float s2 = 0.f;
#pragma unroll
      for (int k = 0; k < 10; ++k) {
        const float d = kaL[b * 10 + k] - u1;
        s2 += aL[b * 10 + k] * expf(-beL[b * 10 + k] * d * d);
      }
      phiL[idx] = s2;
    }
    __syncthreads();
    {
      const int b = tid >> 6, d = tid & 63;
      float wv0 = 0.f, wv1 = 0.f;
      for (int u = 0; u < 48; ++u) {
        wv0 += phiL[b * 96 + u] * (float)tebL[(b * 96 + u) * 64 + d];
        wv1 += phiL[b * 96 + 48 + u] * (float)tebL[(b * 96 + 48 + u) * 64 + d];
      }
      wL[tid] = (f16)(wv0 + wv1);
    }
    __syncthreads();
    if (tid < 64) {  // w(t) -> L1(t+1), L2(t), L3(t)
      const u64 wq = ((u64*)wL)[tid];
      const int bg = b0 + (tid >> 4), d0 = (tid & 15) * 4;
      stU8(A1 + (size_t)((t + 1) & 1) * 64 * P1 + bg * P1 + d0, wq);
      stU8(A2 + (size_t)(t & 1) * 64 * P2 + bg * P2 + d0, wq);
      stU8(A3 + (size_t)(t & 1) * 64 * P3 + bg * P3 + d0, wq);
    }
    arriveS(sl, SB_ATT + ab, t);
  }
}

// ---- OUT staging chunk (compile-time KN) ----
template <int KN>
DI void out_chunk(const f16* Ap, const f16x8* wm, f16* stg, int tid, int wave,
                  int quad, int ln16, f32x4& acc) {
  u64 lo[KN], hi[KN];
#pragma unroll
  for (int j = 0; j < KN; ++j) {
    const int i = tid + j * 256;
    const int r = i / (KN * 4), c16 = i % (KN * 4);
    const f16* p = Ap + (size_t)r * PM + c16 * 8;
    lo[j] = ldU8(p);
    hi[j] = ldU8(p + 4);
  }
  __syncthreads();
#pragma unroll
  for (int j = 0; j < KN; ++j) {
    const int i = tid + j * 256;
    const int r = i / (KN * 4), c16 = i % (KN * 4);
    u64* q = (u64*)(stg + r * SP + c16 * 8);
    q[0] = lo[j];
    q[1] = hi[j];
  }
  __syncthreads();
#pragma unroll
  for (int ksl = 0; ksl < KN; ++ksl) {
    const f16x8 a = *(const f16x8*)(stg + (wave * 16 + ln16) * SP + ksl * 32 + quad * 8);
    acc = __builtin_amdgcn_mfma_f32_16x16x32_f16(a, wm[ksl], acc, 0, 0, 0);
  }
}

// ---- output role (8 WGs): wave-per-m16, K=40 (pad ks38-39 skipped) ----
DI void out_role(char* ws, char* smem, int nt) {
  const int tid = threadIdx.x;
  const int wave = tid >> 6, lane = tid & 63, ln16 = lane & 15, quad = lane >> 4;
  const f16* WM = (const f16*)(ws + OFF_WM);
  const f16* AM = (const f16*)(ws + OFF_AM);
  float* resb = (float*)(ws + OFF_RES);
  int* sl = (int*)(ws + OFF_FLG);
  f16* stg = (f16*)smem;                  // 34816
  float* bmL = (float*)(smem + 34816);    // 64
  int* doom = (int*)(smem + 59384);
  f16x8 wm[38];
#pragma unroll
  for (int i = 0; i < 38; ++i)
    wm[i] = *(const f16x8*)(WM + (size_t)(nt * 16 + ln16) * PM + i * 32 + quad * 8);
  if (tid < 16) bmL[tid] = ((const float*)(ws + OFF_BM))[nt * 16 + tid];
  if (tid == 0) *doom = 0;
  __syncthreads();

  for (int t = 0; t < Tn; ++t) {
    waitR(sl, doom, SB_L1B, 25, t, SB_L2, 25, t, SB_L3, 25, t, 0, 0, 0);
    const f16* Ap = AM + (size_t)(t & 3) * 64 * PM;
    f32x4 acc = f32x4{0.f, 0.f, 0.f, 0.f};
    out_chunk<8>(Ap + 0 * 32, wm + 0, stg, tid, wave, quad, ln16, acc);
    out_chunk<8>(Ap + 8 * 32, wm + 8, stg, tid, wave, quad, ln16, acc);
    out_chunk<8>(Ap + 16 * 32, wm + 16, stg, tid, wave, quad, ln16, acc);
    out_chunk<8>(Ap + 24 * 32, wm + 24, stg, tid, wave, quad, ln16, acc);
    out_chunk<6>(Ap + 32 * 32, wm + 32, stg, tid, wave, quad, ln16, acc);
#pragma unroll
    for (int e = 0; e < 4; ++e) {  // C-layout: col=lane&15, row=quad*4+e
      const int m = wave * 16 + quad * 4 + e;
      resb[((size_t)t * 64 + m) * 128 + nt * 16 + ln16] = acc[e] + bmL[ln16];
    }
    arriveS(sl, SB_OUT + nt, t);
  }
}

__global__ void __launch_bounds__(256, 1) coop_kernel(char* ws, const float* x, const float* Ww) {
  __shared__ char smem[59392];
  const int id = (int)blockIdx.x;
  if (id < 25) l1_role(ws, smem, id, x, Ww);
  else if (id < 50) l2_role(ws, smem, id - 25, x);
  else if (id < 75) l3_role(ws, smem, id - 50, x);
  else if (id < 91) att_role(ws, smem, id - 75);
  else out_role(ws, smem, id - 91);
}

// ---- init: f16 weight layouts, zero A-buffers, slots, teb ----
__global__ void init_build(char* ws, const int* tok, const float* emb,
                           const float* Wih1, const float* Whh1, const float* bih1, const float* bhh1,
                           const float* Wih2, const float* Whh2, const float* bih2, const float* bhh2,
                           const float* Wih3, const float* Whh3, const float* bih3, const float* bhh3,
                           const float* bw, const float* Wm, const float* bm) {
  const int blk = (int)blockIdx.x, tid = (int)threadIdx.x;
  if (blk < 1600) {
    const int j = blk;
    f16* W1 = (f16*)(ws + OFF_W1) + (size_t)j * P1;
    f16* W2 = (f16*)(ws + OFF_W2) + (size_t)j * P2;
    f16* W3 = (f16*)(ws + OFF_W3) + (size_t)j * P2;
    for (int c = tid; c < P1; c += 256) {
      float v = 0.f;
      if (c < 64) v = Wih1[(size_t)j * 67 + 3 + c];
      else if (c < 464) v = Whh1[(size_t)j * 400 + c - 64];
      else if (c < 467) v = Wih1[(size_t)j * 67 + c - 464];
      W1[c] = (f16)v;
    }
    for (int c = tid; c < P2; c += 256) {
      float v2 = 0.f, v3 = 0.f;
      if (c < 64) { v2 = Wih2[(size_t)j * 467 + 403 + c]; v3 = Wih3[(size_t)j * 467 + 403 + c]; }
      else if (c < 464) { v2 = Wih2[(size_t)j * 467 + 3 + c - 64]; v3 = Wih3[(size_t)j * 467 + 3 + c - 64]; }
      else if (c < 467) { v2 = Wih2[(size_t)j * 467 + c - 464]; v3 = Wih3[(size_t)j * 467 + c - 464]; }
      else if (c >= 480 && c < 880) { v2 = Whh2[(size_t)j * 400 + c - 480]; v3 = Whh3[(size_t)j * 400 + c - 480]; }
      W2[c] = (f16)v2;
      W3[c] = (f16)v3;
    }
  } else if (blk < 1728) {
    const int r = blk - 1600;
    f16* WMp = (f16*)(ws + OFF_WM) + (size_t)r * PM;
    for (int c = tid; c < PM; c += 256) {
      const float v = (r < 121 && c < 1200) ? Wm[(size_t)r * 1200 + c] : 0.f;
      WMp[c] = (f16)v;
    }
  } else if (blk == 1728) {
    float* bs1 = (float*)(ws + OFF_BS1);
    float* bs2 = (float*)(ws + OFF_BS2);
    float* bs3 = (float*)(ws + OFF_BS3);
    for (int i = tid; i < 1600; i += 256) {
      bs1[i] = bih1[i] + bhh1[i];
      bs2[i] = bih2[i] + bhh2[i];
      bs3[i] = bih3[i] + bhh3[i];
    }
    float* bwp = (float*)(ws + OFF_BW);
    if (tid < 32) bwp[tid] = (tid < 30) ? bw[tid] : 0.f;
    float* bmp = (float*)(ws + OFF_BM);
    if (tid < 128) bmp[tid] = (tid < 121) ? bm[tid] : 0.f;
  } else if (blk == 1729) {
    int* fl = (int*)(ws + OFF_FLG);
    for (int i = tid; i < NSLOT; i += 256) fl[i] = -1;  // t<0 presets satisfied
  } else if (blk < 1762) {
    unsigned* az = (unsigned*)(ws + OFF_A1);  // A1,A2,A3,AM contiguous
    const int n = (int)((SZ_A1 + 2 * SZ_A2 + SZ_AM) / 4);
    for (int i = (blk - 1730) * 256 + tid; i < n; i += 32 * 256) az[i] = 0u;
  } else {
    f16* tebp = (f16*)(ws + OFF_TEB);
    const int n = 64 * 96 * 64;
    for (int i = (blk - 1762) * 256 + tid; i < n; i += 128 * 256) {
      const int b = i / (96 * 64);
      const int rem = i % (96 * 64);
      const int u = rem >> 6, d = rem & 63;
      const int tk = tok[b * 96 + u];
      tebp[i] = (f16)emb[(size_t)tk * 64 + d];
    }
  }
}

// ---- epilogue: res -> (eos, softmax pi, mu, sigma, rho) ----
__global__ void postproc(const char* ws, float* out) {
  __shared__ float r[50 * 128];
  __shared__ float mx[50], dn[50];
  const float* resb = (const float*)(ws + OFF_RES);
  const int tid = (int)threadIdx.x;
  const int b = (int)blockIdx.x >> 4;
  const int t0 = ((int)blockIdx.x & 15) * 50;
  for (int idx = tid; idx < 50 * 128; idx += 256) {
    const int tt = idx >> 7, c = idx & 127;
    r[idx] = resb[((size_t)(t0 + tt) * 64 + b) * 128 + c];
  }
  __syncthreads();
  if (tid < 50) {
    float m = -1e30f;
    for (int k = 0; k < 20; ++k) m = fmaxf(m, r[tid * 128 + 1 + k]);
    float s = 0.f;
    for (int k = 0; k < 20; ++k) s += expf(r[tid * 128 + 1 + k] - m);
    mx[tid] = m;
    dn[tid] = 1.f / s;
  }
  __syncthreads();
  for (int idx = tid; idx < 50; idx += 256)
    out[O_EOS + (size_t)b * Tn + t0 + idx] = r[idx * 128];
  for (int idx = tid; idx < 50 * 20; idx += 256) {
    const int tt = idx / 20, k = idx % 20;
    const size_t o = ((size_t)b * Tn + t0 + tt) * 20 + k;
    const float* rr = &r[tt * 128];
    out[O_PI + o] = expf(rr[1 + k] - mx[tt]) * dn[tt];
    out[O_MUX + o] = rr[21 + k];
    out[O_MUY + o] = rr[41 + k];
    out[O_SX + o] = expf(rr[61 + k]) + 1e-6f;
    out[O_SY + o] = expf(rr[81 + k]) + 1e-6f;
    out[O_RHO + o] = tanhf(rr[101 + k]) * 0.999f;
  }
}

extern "C" void kernel_launch(void* const* d_in, const int* in_sizes, int n_in,
                              void* d_out, int out_size, void* d_ws, size_t ws_size,
                              hipStream_t stream) {
  const float* x = (const float*)d_in[0];
  const int* tok = (const int*)d_in[1];
  const float* emb = (const float*)d_in[2];
  const float* Wih1 = (const float*)d_in[3];
  const float* Whh1 = (const float*)d_in[4];
  const float* bih1 = (const float*)d_in[5];
  const float* bhh1 = (const float*)d_in[6];
  const float* Wih2 = (const float*)d_in[7];
  const float* Whh2 = (const float*)d_in[8];
  const float* bih2 = (const float*)d_in[9];
  const float* bhh2 = (const float*)d_in[10];
  const float* Wih3 = (const float*)d_in[11];
  const float* Whh3 = (const float*)d_in[12];
  const float* bih3 = (const float*)d_in[13];
  const float* bhh3 = (const float*)d_in[14];
  const float* Ww = (const float*)d_in[15];
  const float* bw = (const float*)d_in[16];
  const float* Wm = (const float*)d_in[17];
  const float* bm = (const float*)d_in[18];
  char* ws = (char*)d_ws;
  float* out = (float*)d_out;

  hipLaunchKernelGGL(init_build, dim3(1890), dim3(256), 0, stream,
                     ws, tok, emb, Wih1, Whh1, bih1, bhh1, Wih2, Whh2, bih2, bhh2,
                     Wih3, Whh3, bih3, bhh3, bw, Wm, bm);

  hipLaunchKernelGGL(coop_kernel, dim3(NWG), dim3(256), 0, stream, ws, x, Ww);

  hipLaunchKernelGGL(postproc, dim3(1024), dim3(256), 0, stream, ws, out);
}

// Round 6
// 7767.216 us; speedup vs baseline: 1.3414x; 1.3414x over previous
//
#include <hip/hip_runtime.h>

// ============================================================================
// R13: R11 structure (best verified) + in-phase shaving, no sync-graph change.
//  - Fast native transcendentals (__expf / v_rcp) in LSTM finish + ATT
//    (overflow-safe tanh via exp(-2|v|); sigm's rcp(1+inf)=0 limit correct).
//  - w-load latency hidden: waitR(ATT) moved before mfma4+1; w stage loads
//    issued under those MFMAs (L1/L2/L3). Barrier count unchanged.
//  - SP 272 -> 264: staging row stride 4 mod 32 dwords -> 2-way (free) LDS
//    bank access instead of 4-way on every staging MFMA read.
//  R12 lesson: each extra waitR+arrive pair costs ~0.5 us of serial path.
// Label: "R13 fast-transcendentals + hidden w-load + SP264"
// ============================================================================

#define DI __device__ __forceinline__

typedef _Float16 f16;
typedef _Float16 f16x8 __attribute__((ext_vector_type(8)));
typedef _Float16 f16x4 __attribute__((ext_vector_type(4)));
typedef float f32x4 __attribute__((ext_vector_type(4)));
typedef unsigned long long u64;
typedef unsigned u32;

constexpr int Tn = 800, Un = 96, Hn = 400;
constexpr int P1 = 520, P2 = 904, P3 = 904, PM = 1288;
constexpr int NWG = 99;
constexpr int SP = 264;  // LDS staging pitch (f16); 264*2B=132dw = 4 mod 32

constexpr size_t OFF_W1 = 0;
constexpr size_t SZ_W1 = (size_t)1600 * P1 * 2;
constexpr size_t OFF_W2 = OFF_W1 + SZ_W1;
constexpr size_t SZ_W2 = (size_t)1600 * P2 * 2;
constexpr size_t OFF_W3 = OFF_W2 + SZ_W2;
constexpr size_t OFF_WM = OFF_W3 + SZ_W2;
constexpr size_t SZ_WM = (size_t)128 * PM * 2;
constexpr size_t OFF_A1 = OFF_WM + SZ_WM;
constexpr size_t SZ_A1 = (size_t)2 * 64 * P1 * 2;
constexpr size_t OFF_A2 = OFF_A1 + SZ_A1;
constexpr size_t SZ_A2 = (size_t)2 * 64 * P2 * 2;
constexpr size_t OFF_A3 = OFF_A2 + SZ_A2;
constexpr size_t OFF_AM = OFF_A3 + SZ_A2;
constexpr size_t SZ_AM = (size_t)4 * 64 * PM * 2;   // quad-buffered (OUT lag)
constexpr size_t OFF_TEB = OFF_AM + SZ_AM;
constexpr size_t SZ_TEB = (size_t)64 * 96 * 64 * 2;
constexpr size_t OFF_BS1 = OFF_TEB + SZ_TEB;
constexpr size_t OFF_BS2 = OFF_BS1 + 6400;
constexpr size_t OFF_BS3 = OFF_BS2 + 6400;
constexpr size_t OFF_BW = OFF_BS3 + 6400;
constexpr size_t OFF_BM = OFF_BW + 128;
constexpr size_t OFF_FLG = OFF_BM + 512;
constexpr size_t SZ_FLG = (size_t)808 * 5 * 16 * 4;  // region reused: flags + PB
constexpr size_t OFF_PB = OFF_FLG + 4096;            // 25*64*32 f32 = 204800 B
constexpr size_t OFF_RES = OFF_FLG + SZ_FLG;

constexpr size_t O_EOS = 0, O_PI = 51200, O_MUX = 1075200, O_MUY = 2099200;
constexpr size_t O_SX = 3123200, O_SY = 4147200, O_RHO = 5171200;

// slot bases: one int per (role, wg)
constexpr int SB_L1 = 0;     // 25 slots
constexpr int SB_ATT = 32;   // 16 slots
constexpr int SB_L2 = 64;    // 25 slots
constexpr int SB_L3 = 96;    // 25 slots
constexpr int SB_OUT = 128;  // 8 slots
constexpr int NSLOT = 160;

constexpr int GUARD_FLAG = 1200000;

// ---- sc1 LLC data movers ----
DI u64 ldU8(const f16* p) {
  return __hip_atomic_load((const u64*)p, __ATOMIC_RELAXED, __HIP_MEMORY_SCOPE_AGENT);
}
DI void stU8(f16* p, u64 u) {
  __hip_atomic_store((u64*)p, u, __ATOMIC_RELAXED, __HIP_MEMORY_SCOPE_AGENT);
}
DI void stU8u(void* p, u64 u) {
  __hip_atomic_store((u64*)p, u, __ATOMIC_RELAXED, __HIP_MEMORY_SCOPE_AGENT);
}
DI u32 ldU4(const u32* p) {
  return __hip_atomic_load(p, __ATOMIC_RELAXED, __HIP_MEMORY_SCOPE_AGENT);
}
DI void stA4(f16* p, f16x4 v) {
  union { f16x4 v; u64 u; } c; c.v = v;
  stU8(p, c.u);
}
DI u64 pkf(float a, float b) {
  return (u64)__builtin_bit_cast(u32, a) | ((u64)__builtin_bit_cast(u32, b) << 32);
}

// ---- fast transcendentals (native v_exp / v_rcp) ----
// sigm: v->-inf: __expf(-v)=inf, rcp(1+inf)=0 (correct); v->+inf: 1 (correct)
DI float sigm(float v) {
  return __builtin_amdgcn_rcpf(1.f + __expf(-v));
}
// tanh via exp(-2|v|) in (0,1]: never overflows; sign restored
DI float ftanh(float v) {
  const float a = fabsf(v);
  const float e = __expf(-2.f * a);
  const float m = (1.f - e) * __builtin_amdgcn_rcpf(1.f + e);
  return v < 0.f ? -m : m;
}

// ---- slot wait: up to 4 ranges of (base, count, t_required) ----
DI void waitR(int* sl, int* doom,
              int b0, int n0, int q0, int b1, int n1, int q1,
              int b2, int n2, int q2, int b3, int n3, int q3) {
  if (!*doom) {
    if (threadIdx.x < 64) {
      const int l = (int)threadIdx.x;
      int sA = -1, qA = 0, sB = -1, qB = 0;
      {
        int idx = l;
        if (idx < n0) { sA = b0 + idx; qA = q0; }
        else { idx -= n0;
          if (idx < n1) { sA = b1 + idx; qA = q1; }
          else { idx -= n1;
            if (idx < n2) { sA = b2 + idx; qA = q2; }
            else { idx -= n2;
              if (idx < n3) { sA = b3 + idx; qA = q3; } } } }
      }
      {
        int idx = l + 64;
        if (idx < n0) { sB = b0 + idx; qB = q0; }
        else { idx -= n0;
          if (idx < n1) { sB = b1 + idx; qB = q1; }
          else { idx -= n1;
            if (idx < n2) { sB = b2 + idx; qB = q2; }
            else { idx -= n2;
              if (idx < n3) { sB = b3 + idx; qB = q3; } } } }
      }
      int okA = (sA < 0) ? 1 : 0, okB = (sB < 0) ? 1 : 0;
      int guard = 0;
      for (;;) {
        if (!okA)
          okA = (__hip_atomic_load(sl + sA, __ATOMIC_RELAXED, __HIP_MEMORY_SCOPE_AGENT) >= qA) ? 1 : 0;
        if (!okB)
          okB = (__hip_atomic_load(sl + sB, __ATOMIC_RELAXED, __HIP_MEMORY_SCOPE_AGENT) >= qB) ? 1 : 0;
        if (__all(okA & okB)) break;
        __builtin_amdgcn_s_sleep(1);
        if (++guard > GUARD_FLAG) { if (l == 0) *doom = 1; break; }  // fail visible
      }
    }
  }
  __syncthreads();
}
// ---- arrive: syncthreads drains all waves' sc1 stores before the slot store
DI void arriveS(int* sl, int slot, int t) {
  __syncthreads();
  if (threadIdx.x == 0)
    __hip_atomic_store(sl + slot, t, __ATOMIC_RELAXED, __HIP_MEMORY_SCOPE_AGENT);
}

// ---- staging split: issue all loads first, write LDS later ----
template <int KN, int PITCH_>
DI void stage_ld(const f16* Ain, int tid, u64* lo, u64* hi) {
#pragma unroll
  for (int j = 0; j < KN; ++j) {
    const int i = tid + j * 256;
    const int r = i / (KN * 4), c16 = i % (KN * 4);
    const f16* p = Ain + (size_t)r * PITCH_ + c16 * 8;
    lo[j] = ldU8(p);
    hi[j] = ldU8(p + 4);
  }
}
template <int KN>
DI void stage_wr(f16* stg, int tid, const u64* lo, const u64* hi) {
#pragma unroll
  for (int j = 0; j < KN; ++j) {
    const int i = tid + j * 256;
    const int r = i / (KN * 4), c16 = i % (KN * 4);
    u64* q = (u64*)(stg + r * SP + c16 * 8);
    q[0] = lo[j];
    q[1] = hi[j];
  }
}
template <int KN>
DI void mfma_blk(const f16x8* wr, const f16* stg, int quad, int ln16, f32x4 acc[4]) {
#pragma unroll
  for (int ksl = 0; ksl < KN; ++ksl) {
    const int kc = ksl * 32 + quad * 8;
#pragma unroll
    for (int mt = 0; mt < 4; ++mt) {
      const f16x8 a = *(const f16x8*)(stg + (mt * 16 + ln16) * SP + kc);
      acc[mt] = __builtin_amdgcn_mfma_f32_16x16x32_f16(a, wr[ksl], acc[mt], 0, 0, 0);
    }
  }
}

// ---- ks14 staging: A cols 448..463 + x(t) direct from global ----
DI void stage_ks14_ld(const f16* Ap, int pitch, const float* x, int t, int tid,
                      u64& sp, float& x0, float& x1, float& x2) {
  const int r = tid >> 2, cc = (tid & 3) * 4;
  sp = ldU8(Ap + (size_t)r * pitch + 448 + cc);
  if (tid < 64) {
    const float* xp = x + ((size_t)tid * Tn + t) * 3;
    x0 = xp[0]; x1 = xp[1]; x2 = xp[2];
  } else { x0 = x1 = x2 = 0.f; }
}
DI void stage_ks14_wr(f16* stg, int tid, u64 sp, float x0, float x1, float x2) {
  const int r = tid >> 2, cc = (tid & 3) * 4;
  *(u64*)(stg + r * SP + 128 + cc) = sp;         // LDS cols 128..143
  if (tid < 64) {
    union { f16 h[4]; u64 u; } cx;
    cx.h[0] = (f16)x0; cx.h[1] = (f16)x1; cx.h[2] = (f16)x2; cx.h[3] = (f16)0.f;
    *(u64*)(stg + tid * SP + 144) = cx.u;        // LDS cols 144..147
    *(u64*)(stg + tid * SP + 148) = 0ull;        // cols 148..159 zeroed
    *(u64*)(stg + tid * SP + 152) = 0ull;
    *(u64*)(stg + tid * SP + 156) = 0ull;
  }
}

// ---- gate finish (L2/L3): cross-wave reduce + LSTM nonlin + h stores ----
DI void gate_finish(f32x4 acc[4], float* red, float* cst, const float* bL, int tid,
                    int quad, int ln16, int wave,
                    f16* dA, int pA, f16* dB, int pB, f16* dC, int pC) {
#pragma unroll
  for (int mt = 0; mt < 4; ++mt)
#pragma unroll
    for (int r = 0; r < 4; ++r)
      red[wave * 1024 + (mt * 16 + quad * 4 + r) * 16 + ln16] = acc[mt][r];
  __syncthreads();
  {
    const int oi = tid * 4, b = oi >> 4, j0 = oi & 15;
    f32x4 gi = *(f32x4*)&red[oi];
    f32x4 gf = *(f32x4*)&red[1024 + oi];
    f32x4 gg = *(f32x4*)&red[2048 + oi];
    f32x4 go = *(f32x4*)&red[3072 + oi];
    f32x4 c = *(f32x4*)&cst[oi];
    f16x4 hv;
#pragma unroll
    for (int e = 0; e < 4; ++e) {
      const float iv = sigm(gi[e] + bL[j0 + e]);
      const float fv = sigm(gf[e] + bL[16 + j0 + e]);
      const float gv = ftanh(gg[e] + bL[32 + j0 + e]);
      const float ov = sigm(go[e] + bL[48 + j0 + e]);
      const float cn = fv * c[e] + iv * gv;
      c[e] = cn;
      hv[e] = (f16)(ov * ftanh(cn));
    }
    *(f32x4*)&cst[oi] = c;
    stA4(dA + b * pA + j0, hv);
    stA4(dB + b * pB + j0, hv);
    if (dC != nullptr) stA4(dC + b * pC + j0, hv);
  }
}

// ---- gate finish (L1): + in-register f32 p-partial -> PB stores (FIRST) ----
DI void gate_finish_l1(f32x4 acc[4], float* red, float* cst, const float* bL,
                       const float* wwL, int tid, int quad, int ln16, int wave,
                       u32* PBu, int jb,
                       f16* dA, int pA, f16* dB, int pB, f16* dC, int pC) {
#pragma unroll
  for (int mt = 0; mt < 4; ++mt)
#pragma unroll
    for (int r = 0; r < 4; ++r)
      red[wave * 1024 + (mt * 16 + quad * 4 + r) * 16 + ln16] = acc[mt][r];
  __syncthreads();
  const int oi = tid * 4, b = oi >> 4, j0 = oi & 15;
  f32x4 gi = *(f32x4*)&red[oi];
  f32x4 gf = *(f32x4*)&red[1024 + oi];
  f32x4 gg = *(f32x4*)&red[2048 + oi];
  f32x4 go = *(f32x4*)&red[3072 + oi];
  f32x4 c = *(f32x4*)&cst[oi];
  float hq[4];
  f16x4 hv;
#pragma unroll
  for (int e = 0; e < 4; ++e) {
    const float iv = sigm(gi[e] + bL[j0 + e]);
    const float fv = sigm(gf[e] + bL[16 + j0 + e]);
    const float gv = ftanh(gg[e] + bL[32 + j0 + e]);
    const float ov = sigm(go[e] + bL[48 + j0 + e]);
    const float cn = fv * c[e] + iv * gv;
    c[e] = cn;
    hq[e] = ov * ftanh(cn);
    hv[e] = (f16)hq[e];
  }
  *(f32x4*)&cst[oi] = c;
  // p-partial over this WG's 16 H-cols (f32)
  float p[30];
#pragma unroll
  for (int r = 0; r < 30; ++r) {
    const f32x4 wv = *(const f32x4*)&wwL[r * 16 + j0];
    p[r] = wv[0] * hq[0] + wv[1] * hq[1] + wv[2] * hq[2] + wv[3] * hq[3];
  }
#pragma unroll
  for (int r = 0; r < 30; ++r) {
    p[r] += __shfl_xor(p[r], 1);
    p[r] += __shfl_xor(p[r], 2);
  }
  {
    const int s4 = tid & 3;
    u64* drow = (u64*)(PBu + (size_t)(jb * 64 + b) * 32);
    if (s4 == 0) {
      stU8u(drow + 0, pkf(p[0], p[1]));   stU8u(drow + 1, pkf(p[2], p[3]));
      stU8u(drow + 2, pkf(p[4], p[5]));   stU8u(drow + 3, pkf(p[6], p[7]));
    } else if (s4 == 1) {
      stU8u(drow + 4, pkf(p[8], p[9]));   stU8u(drow + 5, pkf(p[10], p[11]));
      stU8u(drow + 6, pkf(p[12], p[13])); stU8u(drow + 7, pkf(p[14], p[15]));
    } else if (s4 == 2) {
      stU8u(drow + 8, pkf(p[16], p[17])); stU8u(drow + 9, pkf(p[18], p[19]));
      stU8u(drow + 10, pkf(p[20], p[21])); stU8u(drow + 11, pkf(p[22], p[23]));
    } else {
      stU8u(drow + 12, pkf(p[24], p[25])); stU8u(drow + 13, pkf(p[26], p[27]));
      stU8u(drow + 14, pkf(p[28], p[29]));
    }
  }
  stA4(dA + b * pA + j0, hv);
  stA4(dB + b * pB + j0, hv);
  if (dC != nullptr) stA4(dC + b * pC + j0, hv);
}

// ---- L1 role (25 WGs) ----
DI void l1_role(char* ws, char* smem, int jb, const float* x, const float* Ww) {
  const int tid = threadIdx.x;
  const int wave = tid >> 6, lane = tid & 63, ln16 = lane & 15, quad = lane >> 4;
  const f16* W1 = (const f16*)(ws + OFF_W1);
  f16* A1 = (f16*)(ws + OFF_A1);
  f16* A2 = (f16*)(ws + OFF_A2);
  f16* AM = (f16*)(ws + OFF_AM);
  int* sl = (int*)(ws + OFF_FLG);
  u32* PBu = (u32*)(ws + OFF_PB);
  f16* stg = (f16*)smem;                    // 33792 (64 x SP=264 x 2B)
  float* red = (float*)(smem + 34816);      // 16384
  float* cst = (float*)(smem + 51200);      // 4096
  float* bL = (float*)(smem + 55296);       // 256
  float* wwL = (float*)(smem + 55552);      // 1920 ([30][16] Ww slice)
  int* doom = (int*)(smem + 59384);
  const int row = wave * Hn + jb * 16 + ln16;
  f16x8 wr[16];
#pragma unroll
  for (int i = 0; i < 16; ++i) wr[i] = *(const f16x8*)(W1 + (size_t)row * P1 + i * 32 + quad * 8);
  if (tid < 64) bL[tid] = ((const float*)(ws + OFF_BS1))[(tid >> 4) * Hn + jb * 16 + (tid & 15)];
  for (int i = tid; i < 480; i += 256) {
    const int rr = i >> 4, jj = i & 15;
    wwL[i] = Ww[rr * 400 + jb * 16 + jj];
  }
  for (int z = tid; z < 1024; z += 256) cst[z] = 0.f;
  if (tid == 0) *doom = 0;
  __syncthreads();
  for (int t = 0; t < Tn; ++t) {
    const f16* Ap = A1 + (size_t)(t & 1) * 64 * P1;
    f32x4 acc[4];
#pragma unroll
    for (int mt = 0; mt < 4; ++mt) acc[mt] = f32x4{0.f, 0.f, 0.f, 0.f};
    // phase A: h1-rec ks2..14 + x (needs L1(t-1)); WAR: A2 h-slot (L2), AM (OUT)
    waitR(sl, doom, SB_L1, 25, t - 1, SB_L2, 25, t - 2, SB_OUT, 8, t - 4, 0, 0, 0);
    u64 lo2[2], hi2[2];
    {
      u64 lo8[8], hi8[8], lo4[4], hi4[4], sp;
      float x0, x1, x2;
      stage_ld<8, P1>(Ap + 2 * 32, tid, lo8, hi8);
      stage_ld<4, P1>(Ap + 10 * 32, tid, lo4, hi4);
      stage_ks14_ld(Ap, P1, x, t, tid, sp, x0, x1, x2);
      stage_wr<8>(stg, tid, lo8, hi8);
      __syncthreads();
      mfma_blk<8>(wr + 2, stg, quad, ln16, acc);
      __syncthreads();
      stage_wr<4>(stg, tid, lo4, hi4);
      stage_ks14_wr(stg, tid, sp, x0, x1, x2);
      // phase B gate moved here: waitR's internal barrier separates the
      // stage writes above from the MFMA reads below; w-loads issue under
      // the remaining phase-A MFMAs (latency hidden).
      waitR(sl, doom, SB_ATT, 16, t - 1, 0, 0, 0, 0, 0, 0, 0, 0, 0);
      stage_ld<2, P1>(Ap + 0, tid, lo2, hi2);
      mfma_blk<4>(wr + 10, stg, quad, ln16, acc);
      mfma_blk<1>(wr + 14, stg + 128, quad, ln16, acc);
      // ks15 = pure zero padding: skipped
    }
    __syncthreads();
    stage_wr<2>(stg, tid, lo2, hi2);
    __syncthreads();
    mfma_blk<2>(wr + 0, stg, quad, ln16, acc);
    gate_finish_l1(acc, red, cst, bL, wwL, tid, quad, ln16, wave,
                   PBu, jb,
                   A1 + (size_t)((t + 1) & 1) * 64 * P1 + 64 + jb * 16, P1,
                   A2 + (size_t)(t & 1) * 64 * P2 + 64 + jb * 16, P2,
                   AM + (size_t)(t & 3) * 64 * PM + jb * 16, PM);
    arriveS(sl, SB_L1 + jb, t);
  }
}

// ---- L2 role (25 WGs) ----
DI void l2_role(char* ws, char* smem, int jb, const float* x) {
  const int tid = threadIdx.x;
  const int wave = tid >> 6, lane = tid & 63, ln16 = lane & 15, quad = lane >> 4;
  const f16* W2 = (const f16*)(ws + OFF_W2);
  f16* A2 = (f16*)(ws + OFF_A2);
  f16* A3 = (f16*)(ws + OFF_A3);
  f16* AM = (f16*)(ws + OFF_AM);
  int* sl = (int*)(ws + OFF_FLG);
  f16* stg = (f16*)smem;
  float* red = (float*)(smem + 34816);
  float* cst = (float*)(smem + 51200);
  float* bL = (float*)(smem + 55296);
  int* doom = (int*)(smem + 59384);
  const int row = wave * Hn + jb * 16 + ln16;
  f16x8 wr[28];
#pragma unroll
  for (int i = 0; i < 28; ++i) wr[i] = *(const f16x8*)(W2 + (size_t)row * P2 + i * 32 + quad * 8);
  if (tid < 64) bL[tid] = ((const float*)(ws + OFF_BS2))[(tid >> 4) * Hn + jb * 16 + (tid & 15)];
  for (int z = tid; z < 1024; z += 256) cst[z] = 0.f;
  if (tid == 0) *doom = 0;
  __syncthreads();
  for (int t = 0; t < Tn; ++t) {
    const f16* Ap = A2 + (size_t)(t & 1) * 64 * P2;
    f32x4 acc[4];
#pragma unroll
    for (int mt = 0; mt < 4; ++mt) acc[mt] = f32x4{0.f, 0.f, 0.f, 0.f};
    // phase A: h2-rec ks15..27 (own t-1); WAR: A3 h2-slot (L3), AM (OUT)
    waitR(sl, doom, SB_L2, 25, t - 1, SB_L3, 25, t - 2, SB_OUT, 8, t - 4, 0, 0, 0);
    {
      u64 lo8[8], hi8[8], lo5[5], hi5[5];
      stage_ld<8, P2>(Ap + 15 * 32, tid, lo8, hi8);
      stage_ld<5, P2>(Ap + 23 * 32, tid, lo5, hi5);
      stage_wr<8>(stg, tid, lo8, hi8);
      __syncthreads();
      mfma_blk<8>(wr + 15, stg, quad, ln16, acc);
      __syncthreads();
      stage_wr<5>(stg, tid, lo5, hi5);
      __syncthreads();
      mfma_blk<5>(wr + 23, stg, quad, ln16, acc);
    }
    // phase B: h1(t) + x ks2..14 (needs L1(t))
    waitR(sl, doom, SB_L1, 25, t, 0, 0, 0, 0, 0, 0, 0, 0, 0);
    u64 lo2[2], hi2[2];
    {
      u64 lo8[8], hi8[8], lo4[4], hi4[4], sp;
      float x0, x1, x2;
      stage_ld<8, P2>(Ap + 2 * 32, tid, lo8, hi8);
      stage_ld<4, P2>(Ap + 10 * 32, tid, lo4, hi4);
      stage_ks14_ld(Ap, P2, x, t, tid, sp, x0, x1, x2);
      stage_wr<8>(stg, tid, lo8, hi8);
      __syncthreads();
      mfma_blk<8>(wr + 2, stg, quad, ln16, acc);
      __syncthreads();
      stage_wr<4>(stg, tid, lo4, hi4);
      stage_ks14_wr(stg, tid, sp, x0, x1, x2);
      // phase C gate: ATT(t) wait doubles as the barrier; w-loads hidden
      waitR(sl, doom, SB_ATT, 16, t, 0, 0, 0, 0, 0, 0, 0, 0, 0);
      stage_ld<2, P2>(Ap + 0, tid, lo2, hi2);
      mfma_blk<4>(wr + 10, stg, quad, ln16, acc);
      mfma_blk<1>(wr + 14, stg + 128, quad, ln16, acc);
    }
    __syncthreads();
    stage_wr<2>(stg, tid, lo2, hi2);
    __syncthreads();
    mfma_blk<2>(wr + 0, stg, quad, ln16, acc);
    gate_finish(acc, red, cst, bL, tid, quad, ln16, wave,
                A2 + (size_t)((t + 1) & 1) * 64 * P2 + 480 + jb * 16, P2,
                A3 + (size_t)(t & 1) * 64 * P3 + 64 + jb * 16, P3,
                AM + (size_t)(t & 3) * 64 * PM + Hn + jb * 16, PM);
    arriveS(sl, SB_L2 + jb, t);
  }
}

// ---- L3 role (25 WGs) ----
DI void l3_role(char* ws, char* smem, int jb, const float* x) {
  const int tid = threadIdx.x;
  const int wave = tid >> 6, lane = tid & 63, ln16 = lane & 15, quad = lane >> 4;
  const f16* W3 = (const f16*)(ws + OFF_W3);
  f16* A3 = (f16*)(ws + OFF_A3);
  f16* AM = (f16*)(ws + OFF_AM);
  int* sl = (int*)(ws + OFF_FLG);
  f16* stg = (f16*)smem;
  float* red = (float*)(smem + 34816);
  float* cst = (float*)(smem + 51200);
  float* bL = (float*)(smem + 55296);
  int* doom = (int*)(smem + 59384);
  const int row = wave * Hn + jb * 16 + ln16;
  f16x8 wr[28];
#pragma unroll
  for (int i = 0; i < 28; ++i) wr[i] = *(const f16x8*)(W3 + (size_t)row * P3 + i * 32 + quad * 8);
  if (tid < 64) bL[tid] = ((const float*)(ws + OFF_BS3))[(tid >> 4) * Hn + jb * 16 + (tid & 15)];
  for (int z = tid; z < 1024; z += 256) cst[z] = 0.f;
  if (tid == 0) *doom = 0;
  __syncthreads();
  for (int t = 0; t < Tn; ++t) {
    const f16* Ap = A3 + (size_t)(t & 1) * 64 * P3;
    f32x4 acc[4];
#pragma unroll
    for (int mt = 0; mt < 4; ++mt) acc[mt] = f32x4{0.f, 0.f, 0.f, 0.f};
    // phase A: h3-rec ks15..27 (own t-1); WAR: AM (OUT)
    waitR(sl, doom, SB_L3, 25, t - 1, SB_OUT, 8, t - 4, 0, 0, 0, 0, 0, 0);
    {
      u64 lo8[8], hi8[8], lo5[5], hi5[5];
      stage_ld<8, P3>(Ap + 15 * 32, tid, lo8, hi8);
      stage_ld<5, P3>(Ap + 23 * 32, tid, lo5, hi5);
      stage_wr<8>(stg, tid, lo8, hi8);
      __syncthreads();
      mfma_blk<8>(wr + 15, stg, quad, ln16, acc);
      __syncthreads();
      stage_wr<5>(stg, tid, lo5, hi5);
      __syncthreads();
      mfma_blk<5>(wr + 23, stg, quad, ln16, acc);
    }
    // phase B: h2(t) + x ks2..14 (needs L2(t))
    waitR(sl, doom, SB_L2, 25, t, 0, 0, 0, 0, 0, 0, 0, 0, 0);
    u64 lo2[2], hi2[2];
    {
      u64 lo8[8], hi8[8], lo4[4], hi4[4], sp;
      float x0, x1, x2;
      stage_ld<8, P3>(Ap + 2 * 32, tid, lo8, hi8);
      stage_ld<4, P3>(Ap + 10 * 32, tid, lo4, hi4);
      stage_ks14_ld(Ap, P3, x, t, tid, sp, x0, x1, x2);
      stage_wr<8>(stg, tid, lo8, hi8);
      __syncthreads();
      mfma_blk<8>(wr + 2, stg, quad, ln16, acc);
      __syncthreads();
      stage_wr<4>(stg, tid, lo4, hi4);
      stage_ks14_wr(stg, tid, sp, x0, x1, x2);
      waitR(sl, doom, SB_ATT, 16, t, 0, 0, 0, 0, 0, 0, 0, 0, 0);
      stage_ld<2, P3>(Ap + 0, tid, lo2, hi2);
      mfma_blk<4>(wr + 10, stg, quad, ln16, acc);
      mfma_blk<1>(wr + 14, stg + 128, quad, ln16, acc);
    }
    __syncthreads();
    stage_wr<2>(stg, tid, lo2, hi2);
    __syncthreads();
    mfma_blk<2>(wr + 0, stg, quad, ln16, acc);
    gate_finish(acc, red, cst, bL, tid, quad, ln16, wave,
                A3 + (size_t)((t + 1) & 1) * 64 * P3 + 480 + jb * 16, P3,
                AM + (size_t)(t & 3) * 64 * PM + 2 * Hn + jb * 16, PM,
                nullptr, 0);
    arriveS(sl, SB_L3 + jb, t);
  }
}

// ---- attention role (16 WGs x 4 batches): sum PB partials, emit f16 w ----
DI void att_role(char* ws, char* smem, int ab) {
  const int tid = threadIdx.x;
  const int b0 = ab * 4;
  f16* A1 = (f16*)(ws + OFF_A1);
  f16* A2 = (f16*)(ws + OFF_A2);
  f16* A3 = (f16*)(ws + OFF_A3);
  int* sl = (int*)(ws + OFF_FLG);
  const u32* PBu = (const u32*)(ws + OFF_PB);
  f16* tebL = (f16*)smem;                 // 49152
  float* aL = (float*)(smem + 49152);     // 160
  float* beL = (float*)(smem + 49312);    // 160
  float* kaL = (float*)(smem + 49472);    // 160 (persistent kappa)
  float* phiL = (float*)(smem + 49632);   // 1536
  float* bwL = (float*)(smem + 51168);    // 120
  f16* wL = (f16*)(smem + 51296);         // 512
  int* doom = (int*)(smem + 59384);
  for (int i = tid; i < 24576; i += 256)
    tebL[i] = ((const f16*)(ws + OFF_TEB))[(size_t)b0 * 6144 + i];
  if (tid < 40) kaL[tid] = 0.f;
  if (tid < 30) bwL[tid] = ((const float*)(ws + OFF_BW))[tid];
  if (tid == 0) *doom = 0;
  __syncthreads();
  const int bl = tid / 30, r = tid % 30;
  const bool act = tid < 120;
  const u32* pbase = PBu + (size_t)(b0 + (act ? bl : 0)) * 32 + (act ? r : 0);
  for (int t = 0; t < Tn; ++t) {
    // needs L1(t) p-partials; WAR: w slots in A2/A3 consumed by L2/L3 at t-2
    waitR(sl, doom, SB_L1, 25, t, SB_L2, 25, t - 2, SB_L3, 25, t - 2, 0, 0, 0);
    if (act) {
      float s = bwL[r];
#pragma unroll
      for (int jb = 0; jb < 25; ++jb)
        s += __builtin_bit_cast(float, ldU4(pbase + jb * 2048));
      if (r < 10) aL[bl * 10 + r] = __expf(s);
      else if (r < 20) beL[bl * 10 + r - 10] = __expf(s);
      else kaL[bl * 10 + r - 20] += __expf(fminf(5.f, fmaxf(-10.f, s)));
    }
    __syncthreads();
    for (int idx = tid; idx < 384; idx += 256) {
      const int b = idx / 96;
      const float u1 = (float)(idx % 96 + 1);
      float s2 = 0.f;
#pragma unroll
      for (int k = 0; k < 10; ++k) {
        const float d = kaL[b * 10 + k] - u1;
        s2 += aL[b * 10 + k] * __expf(-beL[b * 10 + k] * d * d);
      }
      phiL[idx] = s2;
    }
    __syncthreads();
    {
      const int b = tid >> 6, d = tid & 63;
      float wv0 = 0.f, wv1 = 0.f;
      for (int u = 0; u < 48; ++u) {
        wv0 += phiL[b * 96 + u] * (float)tebL[(b * 96 + u) * 64 + d];
        wv1 += phiL[b * 96 + 48 + u] * (float)tebL[(b * 96 + 48 + u) * 64 + d];
      }
      wL[tid] = (f16)(wv0 + wv1);
    }
    __syncthreads();
    if (tid < 64) {  // w(t) -> L1(t+1), L2(t), L3(t)
      const u64 wq = ((u64*)wL)[tid];
      const int bg = b0 + (tid >> 4), d0 = (tid & 15) * 4;
      stU8(A1 + (size_t)((t + 1) & 1) * 64 * P1 + bg * P1 + d0, wq);
      stU8(A2 + (size_t)(t & 1) * 64 * P2 + bg * P2 + d0, wq);
      stU8(A3 + (size_t)(t & 1) * 64 * P3 + bg * P3 + d0, wq);
    }
    arriveS(sl, SB_ATT + ab, t);
  }
}

// ---- OUT staging chunk (compile-time KN) ----
template <int KN>
DI void out_chunk(const f16* Ap, const f16x8* wm, f16* stg, int tid, int wave,
                  int quad, int ln16, f32x4& acc) {
  u64 lo[KN], hi[KN];
#pragma unroll
  for (int j = 0; j < KN; ++j) {
    const int i = tid + j * 256;
    const int r = i / (KN * 4), c16 = i % (KN * 4);
    const f16* p = Ap + (size_t)r * PM + c16 * 8;
    lo[j] = ldU8(p);
    hi[j] = ldU8(p + 4);
  }
  __syncthreads();
#pragma unroll
  for (int j = 0; j < KN; ++j) {
    const int i = tid + j * 256;
    const int r = i / (KN * 4), c16 = i % (KN * 4);
    u64* q = (u64*)(stg + r * SP + c16 * 8);
    q[0] = lo[j];
    q[1] = hi[j];
  }
  __syncthreads();
#pragma unroll
  for (int ksl = 0; ksl < KN; ++ksl) {
    const f16x8 a = *(const f16x8*)(stg + (wave * 16 + ln16) * SP + ksl * 32 + quad * 8);
    acc = __builtin_amdgcn_mfma_f32_16x16x32_f16(a, wm[ksl], acc, 0, 0, 0);
  }
}

// ---- output role (8 WGs): wave-per-m16, K=40 (pad ks38-39 skipped) ----
DI void out_role(char* ws, char* smem, int nt) {
  const int tid = threadIdx.x;
  const int wave = tid >> 6, lane = tid & 63, ln16 = lane & 15, quad = lane >> 4;
  const f16* WM = (const f16*)(ws + OFF_WM);
  const f16* AM = (const f16*)(ws + OFF_AM);
  float* resb = (float*)(ws + OFF_RES);
  int* sl = (int*)(ws + OFF_FLG);
  f16* stg = (f16*)smem;                  // 33792
  float* bmL = (float*)(smem + 34816);    // 64
  int* doom = (int*)(smem + 59384);
  f16x8 wm[38];
#pragma unroll
  for (int i = 0; i < 38; ++i)
    wm[i] = *(const f16x8*)(WM + (size_t)(nt * 16 + ln16) * PM + i * 32 + quad * 8);
  if (tid < 16) bmL[tid] = ((const float*)(ws + OFF_BM))[nt * 16 + tid];
  if (tid == 0) *doom = 0;
  __syncthreads();

  for (int t = 0; t < Tn; ++t) {
    waitR(sl, doom, SB_L1, 25, t, SB_L2, 25, t, SB_L3, 25, t, 0, 0, 0);
    const f16* Ap = AM + (size_t)(t & 3) * 64 * PM;
    f32x4 acc = f32x4{0.f, 0.f, 0.f, 0.f};
    out_chunk<8>(Ap + 0 * 32, wm + 0, stg, tid, wave, quad, ln16, acc);
    out_chunk<8>(Ap + 8 * 32, wm + 8, stg, tid, wave, quad, ln16, acc);
    out_chunk<8>(Ap + 16 * 32, wm + 16, stg, tid, wave, quad, ln16, acc);
    out_chunk<8>(Ap + 24 * 32, wm + 24, stg, tid, wave, quad, ln16, acc);
    out_chunk<6>(Ap + 32 * 32, wm + 32, stg, tid, wave, quad, ln16, acc);
#pragma unroll
    for (int e = 0; e < 4; ++e) {  // C-layout: col=lane&15, row=quad*4+e
      const int m = wave * 16 + quad * 4 + e;
      resb[((size_t)t * 64 + m) * 128 + nt * 16 + ln16] = acc[e] + bmL[ln16];
    }
    arriveS(sl, SB_OUT + nt, t);
  }
}

__global__ void __launch_bounds__(256, 1) coop_kernel(char* ws, const float* x, const float* Ww) {
  __shared__ char smem[59392];
  const int id = (int)blockIdx.x;
  if (id < 25) l1_role(ws, smem, id, x, Ww);
  else if (id < 50) l2_role(ws, smem, id - 25, x);
  else if (id < 75) l3_role(ws, smem, id - 50, x);
  else if (id < 91) att_role(ws, smem, id - 75);
  else out_role(ws, smem, id - 91);
}

// ---- init: f16 weight layouts, zero A-buffers, slots, teb ----
__global__ void init_build(char* ws, const int* tok, const float* emb,
                           const float* Wih1, const float* Whh1, const float* bih1, const float* bhh1,
                           const float* Wih2, const float* Whh2, const float* bih2, const float* bhh2,
                           const float* Wih3, const float* Whh3, const float* bih3, const float* bhh3,
                           const float* bw, const float* Wm, const float* bm) {
  const int blk = (int)blockIdx.x, tid = (int)threadIdx.x;
  if (blk < 1600) {
    const int j = blk;
    f16* W1 = (f16*)(ws + OFF_W1) + (size_t)j * P1;
    f16* W2 = (f16*)(ws + OFF_W2) + (size_t)j * P2;
    f16* W3 = (f16*)(ws + OFF_W3) + (size_t)j * P2;
    for (int c = tid; c < P1; c += 256) {
      float v = 0.f;
      if (c < 64) v = Wih1[(size_t)j * 67 + 3 + c];
      else if (c < 464) v = Whh1[(size_t)j * 400 + c - 64];
      else if (c < 467) v = Wih1[(size_t)j * 67 + c - 464];
      W1[c] = (f16)v;
    }
    for (int c = tid; c < P2; c += 256) {
      float v2 = 0.f, v3 = 0.f;
      if (c < 64) { v2 = Wih2[(size_t)j * 467 + 403 + c]; v3 = Wih3[(size_t)j * 467 + 403 + c]; }
      else if (c < 464) { v2 = Wih2[(size_t)j * 467 + 3 + c - 64]; v3 = Wih3[(size_t)j * 467 + 3 + c - 64]; }
      else if (c < 467) { v2 = Wih2[(size_t)j * 467 + c - 464]; v3 = Wih3[(size_t)j * 467 + c - 464]; }
      else if (c >= 480 && c < 880) { v2 = Whh2[(size_t)j * 400 + c - 480]; v3 = Whh3[(size_t)j * 400 + c - 480]; }
      W2[c] = (f16)v2;
      W3[c] = (f16)v3;
    }
  } else if (blk < 1728) {
    const int r = blk - 1600;
    f16* WMp = (f16*)(ws + OFF_WM) + (size_t)r * PM;
    for (int c = tid; c < PM; c += 256) {
      const float v = (r < 121 && c < 1200) ? Wm[(size_t)r * 1200 + c] : 0.f;
      WMp[c] = (f16)v;
    }
  } else if (blk == 1728) {
    float* bs1 = (float*)(ws + OFF_BS1);
    float* bs2 = (float*)(ws + OFF_BS2);
    float* bs3 = (float*)(ws + OFF_BS3);
    for (int i = tid; i < 1600; i += 256) {
      bs1[i] = bih1[i] + bhh1[i];
      bs2[i] = bih2[i] + bhh2[i];
      bs3[i] = bih3[i] + bhh3[i];
    }
    float* bwp = (float*)(ws + OFF_BW);
    if (tid < 32) bwp[tid] = (tid < 30) ? bw[tid] : 0.f;
    float* bmp = (float*)(ws + OFF_BM);
    if (tid < 128) bmp[tid] = (tid < 121) ? bm[tid] : 0.f;
  } else if (blk == 1729) {
    int* fl = (int*)(ws + OFF_FLG);
    for (int i = tid; i < NSLOT; i += 256) fl[i] = -1;  // t<0 presets satisfied
  } else if (blk < 1762) {
    unsigned* az = (unsigned*)(ws + OFF_A1);  // A1,A2,A3,AM contiguous
    const int n = (int)((SZ_A1 + 2 * SZ_A2 + SZ_AM) / 4);
    for (int i = (blk - 1730) * 256 + tid; i < n; i += 32 * 256) az[i] = 0u;
  } else {
    f16* tebp = (f16*)(ws + OFF_TEB);
    const int n = 64 * 96 * 64;
    for (int i = (blk - 1762) * 256 + tid; i < n; i += 128 * 256) {
      const int b = i / (96 * 64);
      const int rem = i % (96 * 64);
      const int u = rem >> 6, d = rem & 63;
      const int tk = tok[b * 96 + u];
      tebp[i] = (f16)emb[(size_t)tk * 64 + d];
    }
  }
}

// ---- epilogue: res -> (eos, softmax pi, mu, sigma, rho) ----
__global__ void postproc(const char* ws, float* out) {
  __shared__ float r[50 * 128];
  __shared__ float mx[50], dn[50];
  const float* resb = (const float*)(ws + OFF_RES);
  const int tid = (int)threadIdx.x;
  const int b = (int)blockIdx.x >> 4;
  const int t0 = ((int)blockIdx.x & 15) * 50;
  for (int idx = tid; idx < 50 * 128; idx += 256) {
    const int tt = idx >> 7, c = idx & 127;
    r[idx] = resb[((size_t)(t0 + tt) * 64 + b) * 128 + c];
  }
  __syncthreads();
  if (tid < 50) {
    float m = -1e30f;
    for (int k = 0; k < 20; ++k) m = fmaxf(m, r[tid * 128 + 1 + k]);
    float s = 0.f;
    for (int k = 0; k < 20; ++k) s += expf(r[tid * 128 + 1 + k] - m);
    mx[tid] = m;
    dn[tid] = 1.f / s;
  }
  __syncthreads();
  for (int idx = tid; idx < 50; idx += 256)
    out[O_EOS + (size_t)b * Tn + t0 + idx] = r[idx * 128];
  for (int idx = tid; idx < 50 * 20; idx += 256) {
    const int tt = idx / 20, k = idx % 20;
    const size_t o = ((size_t)b * Tn + t0 + tt) * 20 + k;
    const float* rr = &r[tt * 128];
    out[O_PI + o] = expf(rr[1 + k] - mx[tt]) * dn[tt];
    out[O_MUX + o] = rr[21 + k];
    out[O_MUY + o] = rr[41 + k];
    out[O_SX + o] = expf(rr[61 + k]) + 1e-6f;
    out[O_SY + o] = expf(rr[81 + k]) + 1e-6f;
    out[O_RHO + o] = tanhf(rr[101 + k]) * 0.999f;
  }
}

extern "C" void kernel_launch(void* const* d_in, const int* in_sizes, int n_in,
                              void* d_out, int out_size, void* d_ws, size_t ws_size,
                              hipStream_t stream) {
  const float* x = (const float*)d_in[0];
  const int* tok = (const int*)d_in[1];
  const float* emb = (const float*)d_in[2];
  const float* Wih1 = (const float*)d_in[3];
  const float* Whh1 = (const float*)d_in[4];
  const float* bih1 = (const float*)d_in[5];
  const float* bhh1 = (const float*)d_in[6];
  const float* Wih2 = (const float*)d_in[7];
  const float* Whh2 = (const float*)d_in[8];
  const float* bih2 = (const float*)d_in[9];
  const float* bhh2 = (const float*)d_in[10];
  const float* Wih3 = (const float*)d_in[11];
  const float* Whh3 = (const float*)d_in[12];
  const float* bih3 = (const float*)d_in[13];
  const float* bhh3 = (const float*)d_in[14];
  const float* Ww = (const float*)d_in[15];
  const float* bw = (const float*)d_in[16];
  const float* Wm = (const float*)d_in[17];
  const float* bm = (const float*)d_in[18];
  char* ws = (char*)d_ws;
  float* out = (float*)d_out;

  hipLaunchKernelGGL(init_build, dim3(1890), dim3(256), 0, stream,
                     ws, tok, emb, Wih1, Whh1, bih1, bhh1, Wih2, Whh2, bih2, bhh2,
                     Wih3, Whh3, bih3, bhh3, bw, Wm, bm);

  hipLaunchKernelGGL(coop_kernel, dim3(NWG), dim3(256), 0, stream, ws, x, Ww);

  hipLaunchKernelGGL(postproc, dim3(1024), dim3(256), 0, stream, ws, out);
}

// Round 7
// 6651.762 us; speedup vs baseline: 1.5663x; 1.1677x over previous
//
#include <hip/hip_runtime.h>

// ============================================================================
// R14: R13 + flag-slot line-spreading + SP revert. No sync-graph change.
//  - Each flag slot on its own 128B line (stride 32 ints): kills reader-storm
//    contention on the 2 hot lines every role polls (R10b mechanism, small
//    scale). 3 hops on the L1<->ATT cycle each pay propagate+detect.
//  - SP 264 -> 272: R13's bank-conflict prediction was wrong (11.8M->105.7M
//    measured); revert to known-good.
//  - Keeps R13's fast transcendentals + hidden w-loads (verified +1.4ms).
// Label: "R14 line-spread flags + SP272"
// ============================================================================

#define DI __device__ __forceinline__

typedef _Float16 f16;
typedef _Float16 f16x8 __attribute__((ext_vector_type(8)));
typedef _Float16 f16x4 __attribute__((ext_vector_type(4)));
typedef float f32x4 __attribute__((ext_vector_type(4)));
typedef unsigned long long u64;
typedef unsigned u32;

constexpr int Tn = 800, Un = 96, Hn = 400;
constexpr int P1 = 520, P2 = 904, P3 = 904, PM = 1288;
constexpr int NWG = 99;
constexpr int SP = 272;  // LDS staging pitch (f16) — known-good conflict level

constexpr size_t OFF_W1 = 0;
constexpr size_t SZ_W1 = (size_t)1600 * P1 * 2;
constexpr size_t OFF_W2 = OFF_W1 + SZ_W1;
constexpr size_t SZ_W2 = (size_t)1600 * P2 * 2;
constexpr size_t OFF_W3 = OFF_W2 + SZ_W2;
constexpr size_t OFF_WM = OFF_W3 + SZ_W2;
constexpr size_t SZ_WM = (size_t)128 * PM * 2;
constexpr size_t OFF_A1 = OFF_WM + SZ_WM;
constexpr size_t SZ_A1 = (size_t)2 * 64 * P1 * 2;
constexpr size_t OFF_A2 = OFF_A1 + SZ_A1;
constexpr size_t SZ_A2 = (size_t)2 * 64 * P2 * 2;
constexpr size_t OFF_A3 = OFF_A2 + SZ_A2;
constexpr size_t OFF_AM = OFF_A3 + SZ_A2;
constexpr size_t SZ_AM = (size_t)4 * 64 * PM * 2;   // quad-buffered (OUT lag)
constexpr size_t OFF_TEB = OFF_AM + SZ_AM;
constexpr size_t SZ_TEB = (size_t)64 * 96 * 64 * 2;
constexpr size_t OFF_BS1 = OFF_TEB + SZ_TEB;
constexpr size_t OFF_BS2 = OFF_BS1 + 6400;
constexpr size_t OFF_BS3 = OFF_BS2 + 6400;
constexpr size_t OFF_BW = OFF_BS3 + 6400;
constexpr size_t OFF_BM = OFF_BW + 128;
constexpr size_t OFF_FLG = OFF_BM + 512;
constexpr size_t SZ_FLG = (size_t)808 * 5 * 16 * 4;  // region reused: flags + PB
constexpr size_t OFF_PB = OFF_FLG + 24576;           // after 160*128B flag lines
constexpr size_t OFF_RES = OFF_FLG + SZ_FLG;

constexpr size_t O_EOS = 0, O_PI = 51200, O_MUX = 1075200, O_MUY = 2099200;
constexpr size_t O_SX = 3123200, O_SY = 4147200, O_RHO = 5171200;

// slot bases: one slot per (role, wg); each slot on its own 128B line (x32)
constexpr int SB_L1 = 0;     // 25 slots
constexpr int SB_ATT = 32;   // 16 slots
constexpr int SB_L2 = 64;    // 25 slots
constexpr int SB_L3 = 96;    // 25 slots
constexpr int SB_OUT = 128;  // 8 slots
constexpr int NSLOT = 160;

constexpr int GUARD_FLAG = 1200000;

// ---- sc1 LLC data movers ----
DI u64 ldU8(const f16* p) {
  return __hip_atomic_load((const u64*)p, __ATOMIC_RELAXED, __HIP_MEMORY_SCOPE_AGENT);
}
DI void stU8(f16* p, u64 u) {
  __hip_atomic_store((u64*)p, u, __ATOMIC_RELAXED, __HIP_MEMORY_SCOPE_AGENT);
}
DI void stU8u(void* p, u64 u) {
  __hip_atomic_store((u64*)p, u, __ATOMIC_RELAXED, __HIP_MEMORY_SCOPE_AGENT);
}
DI u32 ldU4(const u32* p) {
  return __hip_atomic_load(p, __ATOMIC_RELAXED, __HIP_MEMORY_SCOPE_AGENT);
}
DI void stA4(f16* p, f16x4 v) {
  union { f16x4 v; u64 u; } c; c.v = v;
  stU8(p, c.u);
}
DI u64 pkf(float a, float b) {
  return (u64)__builtin_bit_cast(u32, a) | ((u64)__builtin_bit_cast(u32, b) << 32);
}

// ---- fast transcendentals (native v_exp / v_rcp) ----
DI float sigm(float v) {
  return __builtin_amdgcn_rcpf(1.f + __expf(-v));
}
DI float ftanh(float v) {
  const float a = fabsf(v);
  const float e = __expf(-2.f * a);
  const float m = (1.f - e) * __builtin_amdgcn_rcpf(1.f + e);
  return v < 0.f ? -m : m;
}

// ---- slot wait: up to 4 ranges of (base, count, t_required); slot idx*32 ----
DI void waitR(int* sl, int* doom,
              int b0, int n0, int q0, int b1, int n1, int q1,
              int b2, int n2, int q2, int b3, int n3, int q3) {
  if (!*doom) {
    if (threadIdx.x < 64) {
      const int l = (int)threadIdx.x;
      int sA = -1, qA = 0, sB = -1, qB = 0;
      {
        int idx = l;
        if (idx < n0) { sA = b0 + idx; qA = q0; }
        else { idx -= n0;
          if (idx < n1) { sA = b1 + idx; qA = q1; }
          else { idx -= n1;
            if (idx < n2) { sA = b2 + idx; qA = q2; }
            else { idx -= n2;
              if (idx < n3) { sA = b3 + idx; qA = q3; } } } }
      }
      {
        int idx = l + 64;
        if (idx < n0) { sB = b0 + idx; qB = q0; }
        else { idx -= n0;
          if (idx < n1) { sB = b1 + idx; qB = q1; }
          else { idx -= n1;
            if (idx < n2) { sB = b2 + idx; qB = q2; }
            else { idx -= n2;
              if (idx < n3) { sB = b3 + idx; qB = q3; } } } }
      }
      int okA = (sA < 0) ? 1 : 0, okB = (sB < 0) ? 1 : 0;
      int guard = 0;
      for (;;) {
        if (!okA)
          okA = (__hip_atomic_load(sl + sA * 32, __ATOMIC_RELAXED, __HIP_MEMORY_SCOPE_AGENT) >= qA) ? 1 : 0;
        if (!okB)
          okB = (__hip_atomic_load(sl + sB * 32, __ATOMIC_RELAXED, __HIP_MEMORY_SCOPE_AGENT) >= qB) ? 1 : 0;
        if (__all(okA & okB)) break;
        __builtin_amdgcn_s_sleep(1);
        if (++guard > GUARD_FLAG) { if (l == 0) *doom = 1; break; }  // fail visible
      }
    }
  }
  __syncthreads();
}
// ---- arrive: syncthreads drains all waves' sc1 stores before the slot store
DI void arriveS(int* sl, int slot, int t) {
  __syncthreads();
  if (threadIdx.x == 0)
    __hip_atomic_store(sl + slot * 32, t, __ATOMIC_RELAXED, __HIP_MEMORY_SCOPE_AGENT);
}

// ---- staging split: issue all loads first, write LDS later ----
template <int KN, int PITCH_>
DI void stage_ld(const f16* Ain, int tid, u64* lo, u64* hi) {
#pragma unroll
  for (int j = 0; j < KN; ++j) {
    const int i = tid + j * 256;
    const int r = i / (KN * 4), c16 = i % (KN * 4);
    const f16* p = Ain + (size_t)r * PITCH_ + c16 * 8;
    lo[j] = ldU8(p);
    hi[j] = ldU8(p + 4);
  }
}
template <int KN>
DI void stage_wr(f16* stg, int tid, const u64* lo, const u64* hi) {
#pragma unroll
  for (int j = 0; j < KN; ++j) {
    const int i = tid + j * 256;
    const int r = i / (KN * 4), c16 = i % (KN * 4);
    u64* q = (u64*)(stg + r * SP + c16 * 8);
    q[0] = lo[j];
    q[1] = hi[j];
  }
}
template <int KN>
DI void mfma_blk(const f16x8* wr, const f16* stg, int quad, int ln16, f32x4 acc[4]) {
#pragma unroll
  for (int ksl = 0; ksl < KN; ++ksl) {
    const int kc = ksl * 32 + quad * 8;
#pragma unroll
    for (int mt = 0; mt < 4; ++mt) {
      const f16x8 a = *(const f16x8*)(stg + (mt * 16 + ln16) * SP + kc);
      acc[mt] = __builtin_amdgcn_mfma_f32_16x16x32_f16(a, wr[ksl], acc[mt], 0, 0, 0);
    }
  }
}

// ---- ks14 staging: A cols 448..463 + x(t) direct from global ----
DI void stage_ks14_ld(const f16* Ap, int pitch, const float* x, int t, int tid,
                      u64& sp, float& x0, float& x1, float& x2) {
  const int r = tid >> 2, cc = (tid & 3) * 4;
  sp = ldU8(Ap + (size_t)r * pitch + 448 + cc);
  if (tid < 64) {
    const float* xp = x + ((size_t)tid * Tn + t) * 3;
    x0 = xp[0]; x1 = xp[1]; x2 = xp[2];
  } else { x0 = x1 = x2 = 0.f; }
}
DI void stage_ks14_wr(f16* stg, int tid, u64 sp, float x0, float x1, float x2) {
  const int r = tid >> 2, cc = (tid & 3) * 4;
  *(u64*)(stg + r * SP + 128 + cc) = sp;         // LDS cols 128..143
  if (tid < 64) {
    union { f16 h[4]; u64 u; } cx;
    cx.h[0] = (f16)x0; cx.h[1] = (f16)x1; cx.h[2] = (f16)x2; cx.h[3] = (f16)0.f;
    *(u64*)(stg + tid * SP + 144) = cx.u;        // LDS cols 144..147
    *(u64*)(stg + tid * SP + 148) = 0ull;        // cols 148..159 zeroed
    *(u64*)(stg + tid * SP + 152) = 0ull;
    *(u64*)(stg + tid * SP + 156) = 0ull;
  }
}

// ---- gate finish (L2/L3): cross-wave reduce + LSTM nonlin + h stores ----
DI void gate_finish(f32x4 acc[4], float* red, float* cst, const float* bL, int tid,
                    int quad, int ln16, int wave,
                    f16* dA, int pA, f16* dB, int pB, f16* dC, int pC) {
#pragma unroll
  for (int mt = 0; mt < 4; ++mt)
#pragma unroll
    for (int r = 0; r < 4; ++r)
      red[wave * 1024 + (mt * 16 + quad * 4 + r) * 16 + ln16] = acc[mt][r];
  __syncthreads();
  {
    const int oi = tid * 4, b = oi >> 4, j0 = oi & 15;
    f32x4 gi = *(f32x4*)&red[oi];
    f32x4 gf = *(f32x4*)&red[1024 + oi];
    f32x4 gg = *(f32x4*)&red[2048 + oi];
    f32x4 go = *(f32x4*)&red[3072 + oi];
    f32x4 c = *(f32x4*)&cst[oi];
    f16x4 hv;
#pragma unroll
    for (int e = 0; e < 4; ++e) {
      const float iv = sigm(gi[e] + bL[j0 + e]);
      const float fv = sigm(gf[e] + bL[16 + j0 + e]);
      const float gv = ftanh(gg[e] + bL[32 + j0 + e]);
      const float ov = sigm(go[e] + bL[48 + j0 + e]);
      const float cn = fv * c[e] + iv * gv;
      c[e] = cn;
      hv[e] = (f16)(ov * ftanh(cn));
    }
    *(f32x4*)&cst[oi] = c;
    stA4(dA + b * pA + j0, hv);
    stA4(dB + b * pB + j0, hv);
    if (dC != nullptr) stA4(dC + b * pC + j0, hv);
  }
}

// ---- gate finish (L1): + in-register f32 p-partial -> PB stores (FIRST) ----
DI void gate_finish_l1(f32x4 acc[4], float* red, float* cst, const float* bL,
                       const float* wwL, int tid, int quad, int ln16, int wave,
                       u32* PBu, int jb,
                       f16* dA, int pA, f16* dB, int pB, f16* dC, int pC) {
#pragma unroll
  for (int mt = 0; mt < 4; ++mt)
#pragma unroll
    for (int r = 0; r < 4; ++r)
      red[wave * 1024 + (mt * 16 + quad * 4 + r) * 16 + ln16] = acc[mt][r];
  __syncthreads();
  const int oi = tid * 4, b = oi >> 4, j0 = oi & 15;
  f32x4 gi = *(f32x4*)&red[oi];
  f32x4 gf = *(f32x4*)&red[1024 + oi];
  f32x4 gg = *(f32x4*)&red[2048 + oi];
  f32x4 go = *(f32x4*)&red[3072 + oi];
  f32x4 c = *(f32x4*)&cst[oi];
  float hq[4];
  f16x4 hv;
#pragma unroll
  for (int e = 0; e < 4; ++e) {
    const float iv = sigm(gi[e] + bL[j0 + e]);
    const float fv = sigm(gf[e] + bL[16 + j0 + e]);
    const float gv = ftanh(gg[e] + bL[32 + j0 + e]);
    const float ov = sigm(go[e] + bL[48 + j0 + e]);
    const float cn = fv * c[e] + iv * gv;
    c[e] = cn;
    hq[e] = ov * ftanh(cn);
    hv[e] = (f16)hq[e];
  }
  *(f32x4*)&cst[oi] = c;
  // p-partial over this WG's 16 H-cols (f32)
  float p[30];
#pragma unroll
  for (int r = 0; r < 30; ++r) {
    const f32x4 wv = *(const f32x4*)&wwL[r * 16 + j0];
    p[r] = wv[0] * hq[0] + wv[1] * hq[1] + wv[2] * hq[2] + wv[3] * hq[3];
  }
#pragma unroll
  for (int r = 0; r < 30; ++r) {
    p[r] += __shfl_xor(p[r], 1);
    p[r] += __shfl_xor(p[r], 2);
  }
  {
    const int s4 = tid & 3;
    u64* drow = (u64*)(PBu + (size_t)(jb * 64 + b) * 32);
    if (s4 == 0) {
      stU8u(drow + 0, pkf(p[0], p[1]));   stU8u(drow + 1, pkf(p[2], p[3]));
      stU8u(drow + 2, pkf(p[4], p[5]));   stU8u(drow + 3, pkf(p[6], p[7]));
    } else if (s4 == 1) {
      stU8u(drow + 4, pkf(p[8], p[9]));   stU8u(drow + 5, pkf(p[10], p[11]));
      stU8u(drow + 6, pkf(p[12], p[13])); stU8u(drow + 7, pkf(p[14], p[15]));
    } else if (s4 == 2) {
      stU8u(drow + 8, pkf(p[16], p[17])); stU8u(drow + 9, pkf(p[18], p[19]));
      stU8u(drow + 10, pkf(p[20], p[21])); stU8u(drow + 11, pkf(p[22], p[23]));
    } else {
      stU8u(drow + 12, pkf(p[24], p[25])); stU8u(drow + 13, pkf(p[26], p[27]));
      stU8u(drow + 14, pkf(p[28], p[29]));
    }
  }
  stA4(dA + b * pA + j0, hv);
  stA4(dB + b * pB + j0, hv);
  if (dC != nullptr) stA4(dC + b * pC + j0, hv);
}

// ---- L1 role (25 WGs) ----
DI void l1_role(char* ws, char* smem, int jb, const float* x, const float* Ww) {
  const int tid = threadIdx.x;
  const int wave = tid >> 6, lane = tid & 63, ln16 = lane & 15, quad = lane >> 4;
  const f16* W1 = (const f16*)(ws + OFF_W1);
  f16* A1 = (f16*)(ws + OFF_A1);
  f16* A2 = (f16*)(ws + OFF_A2);
  f16* AM = (f16*)(ws + OFF_AM);
  int* sl = (int*)(ws + OFF_FLG);
  u32* PBu = (u32*)(ws + OFF_PB);
  f16* stg = (f16*)smem;                    // 34816
  float* red = (float*)(smem + 34816);      // 16384
  float* cst = (float*)(smem + 51200);      // 4096
  float* bL = (float*)(smem + 55296);       // 256
  float* wwL = (float*)(smem + 55552);      // 1920 ([30][16] Ww slice)
  int* doom = (int*)(smem + 59384);
  const int row = wave * Hn + jb * 16 + ln16;
  f16x8 wr[16];
#pragma unroll
  for (int i = 0; i < 16; ++i) wr[i] = *(const f16x8*)(W1 + (size_t)row * P1 + i * 32 + quad * 8);
  if (tid < 64) bL[tid] = ((const float*)(ws + OFF_BS1))[(tid >> 4) * Hn + jb * 16 + (tid & 15)];
  for (int i = tid; i < 480; i += 256) {
    const int rr = i >> 4, jj = i & 15;
    wwL[i] = Ww[rr * 400 + jb * 16 + jj];
  }
  for (int z = tid; z < 1024; z += 256) cst[z] = 0.f;
  if (tid == 0) *doom = 0;
  __syncthreads();
  for (int t = 0; t < Tn; ++t) {
    const f16* Ap = A1 + (size_t)(t & 1) * 64 * P1;
    f32x4 acc[4];
#pragma unroll
    for (int mt = 0; mt < 4; ++mt) acc[mt] = f32x4{0.f, 0.f, 0.f, 0.f};
    // phase A: h1-rec ks2..14 + x (needs L1(t-1)); WAR: A2 h-slot (L2), AM (OUT)
    waitR(sl, doom, SB_L1, 25, t - 1, SB_L2, 25, t - 2, SB_OUT, 8, t - 4, 0, 0, 0);
    u64 lo2[2], hi2[2];
    {
      u64 lo8[8], hi8[8], lo4[4], hi4[4], sp;
      float x0, x1, x2;
      stage_ld<8, P1>(Ap + 2 * 32, tid, lo8, hi8);
      stage_ld<4, P1>(Ap + 10 * 32, tid, lo4, hi4);
      stage_ks14_ld(Ap, P1, x, t, tid, sp, x0, x1, x2);
      stage_wr<8>(stg, tid, lo8, hi8);
      __syncthreads();
      mfma_blk<8>(wr + 2, stg, quad, ln16, acc);
      __syncthreads();
      stage_wr<4>(stg, tid, lo4, hi4);
      stage_ks14_wr(stg, tid, sp, x0, x1, x2);
      // phase B gate here: waitR's internal barrier separates the stage
      // writes above from the MFMA reads below; w-loads issue under the
      // remaining phase-A MFMAs (latency hidden).
      waitR(sl, doom, SB_ATT, 16, t - 1, 0, 0, 0, 0, 0, 0, 0, 0, 0);
      stage_ld<2, P1>(Ap + 0, tid, lo2, hi2);
      mfma_blk<4>(wr + 10, stg, quad, ln16, acc);
      mfma_blk<1>(wr + 14, stg + 128, quad, ln16, acc);
      // ks15 = pure zero padding: skipped
    }
    __syncthreads();
    stage_wr<2>(stg, tid, lo2, hi2);
    __syncthreads();
    mfma_blk<2>(wr + 0, stg, quad, ln16, acc);
    gate_finish_l1(acc, red, cst, bL, wwL, tid, quad, ln16, wave,
                   PBu, jb,
                   A1 + (size_t)((t + 1) & 1) * 64 * P1 + 64 + jb * 16, P1,
                   A2 + (size_t)(t & 1) * 64 * P2 + 64 + jb * 16, P2,
                   AM + (size_t)(t & 3) * 64 * PM + jb * 16, PM);
    arriveS(sl, SB_L1 + jb, t);
  }
}

// ---- L2 role (25 WGs) ----
DI void l2_role(char* ws, char* smem, int jb, const float* x) {
  const int tid = threadIdx.x;
  const int wave = tid >> 6, lane = tid & 63, ln16 = lane & 15, quad = lane >> 4;
  const f16* W2 = (const f16*)(ws + OFF_W2);
  f16* A2 = (f16*)(ws + OFF_A2);
  f16* A3 = (f16*)(ws + OFF_A3);
  f16* AM = (f16*)(ws + OFF_AM);
  int* sl = (int*)(ws + OFF_FLG);
  f16* stg = (f16*)smem;
  float* red = (float*)(smem + 34816);
  float* cst = (float*)(smem + 51200);
  float* bL = (float*)(smem + 55296);
  int* doom = (int*)(smem + 59384);
  const int row = wave * Hn + jb * 16 + ln16;
  f16x8 wr[28];
#pragma unroll
  for (int i = 0; i < 28; ++i) wr[i] = *(const f16x8*)(W2 + (size_t)row * P2 + i * 32 + quad * 8);
  if (tid < 64) bL[tid] = ((const float*)(ws + OFF_BS2))[(tid >> 4) * Hn + jb * 16 + (tid & 15)];
  for (int z = tid; z < 1024; z += 256) cst[z] = 0.f;
  if (tid == 0) *doom = 0;
  __syncthreads();
  for (int t = 0; t < Tn; ++t) {
    const f16* Ap = A2 + (size_t)(t & 1) * 64 * P2;
    f32x4 acc[4];
#pragma unroll
    for (int mt = 0; mt < 4; ++mt) acc[mt] = f32x4{0.f, 0.f, 0.f, 0.f};
    // phase A: h2-rec ks15..27 (own t-1); WAR: A3 h2-slot (L3), AM (OUT)
    waitR(sl, doom, SB_L2, 25, t - 1, SB_L3, 25, t - 2, SB_OUT, 8, t - 4, 0, 0, 0);
    {
      u64 lo8[8], hi8[8], lo5[5], hi5[5];
      stage_ld<8, P2>(Ap + 15 * 32, tid, lo8, hi8);
      stage_ld<5, P2>(Ap + 23 * 32, tid, lo5, hi5);
      stage_wr<8>(stg, tid, lo8, hi8);
      __syncthreads();
      mfma_blk<8>(wr + 15, stg, quad, ln16, acc);
      __syncthreads();
      stage_wr<5>(stg, tid, lo5, hi5);
      __syncthreads();
      mfma_blk<5>(wr + 23, stg, quad, ln16, acc);
    }
    // phase B: h1(t) + x ks2..14 (needs L1(t))
    waitR(sl, doom, SB_L1, 25, t, 0, 0, 0, 0, 0, 0, 0, 0, 0);
    u64 lo2[2], hi2[2];
    {
      u64 lo8[8], hi8[8], lo4[4], hi4[4], sp;
      float x0, x1, x2;
      stage_ld<8, P2>(Ap + 2 * 32, tid, lo8, hi8);
      stage_ld<4, P2>(Ap + 10 * 32, tid, lo4, hi4);
      stage_ks14_ld(Ap, P2, x, t, tid, sp, x0, x1, x2);
      stage_wr<8>(stg, tid, lo8, hi8);
      __syncthreads();
      mfma_blk<8>(wr + 2, stg, quad, ln16, acc);
      __syncthreads();
      stage_wr<4>(stg, tid, lo4, hi4);
      stage_ks14_wr(stg, tid, sp, x0, x1, x2);
      // phase C gate: ATT(t) wait doubles as the barrier; w-loads hidden
      waitR(sl, doom, SB_ATT, 16, t, 0, 0, 0, 0, 0, 0, 0, 0, 0);
      stage_ld<2, P2>(Ap + 0, tid, lo2, hi2);
      mfma_blk<4>(wr + 10, stg, quad, ln16, acc);
      mfma_blk<1>(wr + 14, stg + 128, quad, ln16, acc);
    }
    __syncthreads();
    stage_wr<2>(stg, tid, lo2, hi2);
    __syncthreads();
    mfma_blk<2>(wr + 0, stg, quad, ln16, acc);
    gate_finish(acc, red, cst, bL, tid, quad, ln16, wave,
                A2 + (size_t)((t + 1) & 1) * 64 * P2 + 480 + jb * 16, P2,
                A3 + (size_t)(t & 1) * 64 * P3 + 64 + jb * 16, P3,
                AM + (size_t)(t & 3) * 64 * PM + Hn + jb * 16, PM);
    arriveS(sl, SB_L2 + jb, t);
  }
}

// ---- L3 role (25 WGs) ----
DI void l3_role(char* ws, char* smem, int jb, const float* x) {
  const int tid = threadIdx.x;
  const int wave = tid >> 6, lane = tid & 63, ln16 = lane & 15, quad = lane >> 4;
  const f16* W3 = (const f16*)(ws + OFF_W3);
  f16* A3 = (f16*)(ws + OFF_A3);
  f16* AM = (f16*)(ws + OFF_AM);
  int* sl = (int*)(ws + OFF_FLG);
  f16* stg = (f16*)smem;
  float* red = (float*)(smem + 34816);
  float* cst = (float*)(smem + 51200);
  float* bL = (float*)(smem + 55296);
  int* doom = (int*)(smem + 59384);
  const int row = wave * Hn + jb * 16 + ln16;
  f16x8 wr[28];
#pragma unroll
  for (int i = 0; i < 28; ++i) wr[i] = *(const f16x8*)(W3 + (size_t)row * P2 + i * 32 + quad * 8);
  if (tid < 64) bL[tid] = ((const float*)(ws + OFF_BS3))[(tid >> 4) * Hn + jb * 16 + (tid & 15)];
  for (int z = tid; z < 1024; z += 256) cst[z] = 0.f;
  if (tid == 0) *doom = 0;
  __syncthreads();
  for (int t = 0; t < Tn; ++t) {
    const f16* Ap = A3 + (size_t)(t & 1) * 64 * P3;
    f32x4 acc[4];
#pragma unroll
    for (int mt = 0; mt < 4; ++mt) acc[mt] = f32x4{0.f, 0.f, 0.f, 0.f};
    // phase A: h3-rec ks15..27 (own t-1); WAR: AM (OUT)
    waitR(sl, doom, SB_L3, 25, t - 1, SB_OUT, 8, t - 4, 0, 0, 0, 0, 0, 0);
    {
      u64 lo8[8], hi8[8], lo5[5], hi5[5];
      stage_ld<8, P3>(Ap + 15 * 32, tid, lo8, hi8);
      stage_ld<5, P3>(Ap + 23 * 32, tid, lo5, hi5);
      stage_wr<8>(stg, tid, lo8, hi8);
      __syncthreads();
      mfma_blk<8>(wr + 15, stg, quad, ln16, acc);
      __syncthreads();
      stage_wr<5>(stg, tid, lo5, hi5);
      __syncthreads();
      mfma_blk<5>(wr + 23, stg, quad, ln16, acc);
    }
    // phase B: h2(t) + x ks2..14 (needs L2(t))
    waitR(sl, doom, SB_L2, 25, t, 0, 0, 0, 0, 0, 0, 0, 0, 0);
    u64 lo2[2], hi2[2];
    {
      u64 lo8[8], hi8[8], lo4[4], hi4[4], sp;
      float x0, x1, x2;
      stage_ld<8, P3>(Ap + 2 * 32, tid, lo8, hi8);
      stage_ld<4, P3>(Ap + 10 * 32, tid, lo4, hi4);
      stage_ks14_ld(Ap, P3, x, t, tid, sp, x0, x1, x2);
      stage_wr<8>(stg, tid, lo8, hi8);
      __syncthreads();
      mfma_blk<8>(wr + 2, stg, quad, ln16, acc);
      __syncthreads();
      stage_wr<4>(stg, tid, lo4, hi4);
      stage_ks14_wr(stg, tid, sp, x0, x1, x2);
      waitR(sl, doom, SB_ATT, 16, t, 0, 0, 0, 0, 0, 0, 0, 0, 0);
      stage_ld<2, P3>(Ap + 0, tid, lo2, hi2);
      mfma_blk<4>(wr + 10, stg, quad, ln16, acc);
      mfma_blk<1>(wr + 14, stg + 128, quad, ln16, acc);
    }
    __syncthreads();
    stage_wr<2>(stg, tid, lo2, hi2);
    __syncthreads();
    mfma_blk<2>(wr + 0, stg, quad, ln16, acc);
    gate_finish(acc, red, cst, bL, tid, quad, ln16, wave,
                A3 + (size_t)((t + 1) & 1) * 64 * P3 + 480 + jb * 16, P3,
                AM + (size_t)(t & 3) * 64 * PM + 2 * Hn + jb * 16, PM,
                nullptr, 0);
    arriveS(sl, SB_L3 + jb, t);
  }
}

// ---- attention role (16 WGs x 4 batches): sum PB partials, emit f16 w ----
DI void att_role(char* ws, char* smem, int ab) {
  const int tid = threadIdx.x;
  const int b0 = ab * 4;
  f16* A1 = (f16*)(ws + OFF_A1);
  f16* A2 = (f16*)(ws + OFF_A2);
  f16* A3 = (f16*)(ws + OFF_A3);
  int* sl = (int*)(ws + OFF_FLG);
  const u32* PBu = (const u32*)(ws + OFF_PB);
  f16* tebL = (f16*)smem;                 // 49152
  float* aL = (float*)(smem + 49152);     // 160
  float* beL = (float*)(smem + 49312);    // 160
  float* kaL = (float*)(smem + 49472);    // 160 (persistent kappa)
  float* phiL = (float*)(smem + 49632);   // 1536
  float* bwL = (float*)(smem + 51168);    // 120
  f16* wL = (f16*)(smem + 51296);         // 512
  int* doom = (int*)(smem + 59384);
  for (int i = tid; i < 24576; i += 256)
    tebL[i] = ((const f16*)(ws + OFF_TEB))[(size_t)b0 * 6144 + i];
  if (tid < 40) kaL[tid] = 0.f;
  if (tid < 30) bwL[tid] = ((const float*)(ws + OFF_BW))[tid];
  if (tid == 0) *doom = 0;
  __syncthreads();
  const int bl = tid / 30, r = tid % 30;
  const bool act = tid < 120;
  const u32* pbase = PBu + (size_t)(b0 + (act ? bl : 0)) * 32 + (act ? r : 0);
  for (int t = 0; t < Tn; ++t) {
    // needs L1(t) p-partials; WAR: w slots in A2/A3 consumed by L2/L3 at t-2
    waitR(sl, doom, SB_L1, 25, t, SB_L2, 25, t - 2, SB_L3, 25, t - 2, 0, 0, 0);
    if (act) {
      float s = bwL[r];
#pragma unroll
      for (int jb = 0; jb < 25; ++jb)
        s += __builtin_bit_cast(float, ldU4(pbase + jb * 2048));
      if (r < 10) aL[bl * 10 + r] = __expf(s);
      else if (r < 20) beL[bl * 10 + r - 10] = __expf(s);
      else kaL[bl * 10 + r - 20] += __expf(fminf(5.f, fmaxf(-10.f, s)));
    }
    __syncthreads();
    for (int idx = tid; idx < 384; idx += 256) {
      const int b = idx / 96;
      const float u1 = (float)(idx % 96 + 1);
      float s2 = 0.f;
#pragma unroll
      for (int k = 0; k < 10; ++k) {
        const float d = kaL[b * 10 + k] - u1;
        s2 += aL[b * 10 + k] * __expf(-beL[b * 10 + k] * d * d);
      }
      phiL[idx] = s2;
    }
    __syncthreads();
    {
      const int b = tid >> 6, d = tid & 63;
      float wv0 = 0.f, wv1 = 0.f;
      for (int u = 0; u < 48; ++u) {
        wv0 += phiL[b * 96 + u] * (float)tebL[(b * 96 + u) * 64 + d];
        wv1 += phiL[b * 96 + 48 + u] * (float)tebL[(b * 96 + 48 + u) * 64 + d];
      }
      wL[tid] = (f16)(wv0 + wv1);
    }
    __syncthreads();
    if (tid < 64) {  // w(t) -> L1(t+1), L2(t), L3(t)
      const u64 wq = ((u64*)wL)[tid];
      const int bg = b0 + (tid >> 4), d0 = (tid & 15) * 4;
      stU8(A1 + (size_t)((t + 1) & 1) * 64 * P1 + bg * P1 + d0, wq);
      stU8(A2 + (size_t)(t & 1) * 64 * P2 + bg * P2 + d0, wq);
      stU8(A3 + (size_t)(t & 1) * 64 * P3 + bg * P3 + d0, wq);
    }
    arriveS(sl, SB_ATT + ab, t);
  }
}

// ---- OUT staging chunk (compile-time KN) ----
template <int KN>
DI void out_chunk(const f16* Ap, const f16x8* wm, f16* stg, int tid, int wave,
                  int quad, int ln16, f32x4& acc) {
  u64 lo[KN], hi[KN];
#pragma unroll
  for (int j = 0; j < KN; ++j) {
    const int i = tid + j * 256;
    const int r = i / (KN * 4), c16 = i % (KN * 4);
    const f16* p = Ap + (size_t)r * PM + c16 * 8;
    lo[j] = ldU8(p);
    hi[j] = ldU8(p + 4);
  }
  __syncthreads();
#pragma unroll
  for (int j = 0; j < KN; ++j) {
    const int i = tid + j * 256;
    const int r = i / (KN * 4), c16 = i % (KN * 4);
    u64* q = (u64*)(stg + r * SP + c16 * 8);
    q[0] = lo[j];
    q[1] = hi[j];
  }
  __syncthreads();
#pragma unroll
  for (int ksl = 0; ksl < KN; ++ksl) {
    const f16x8 a = *(const f16x8*)(stg + (wave * 16 + ln16) * SP + ksl * 32 + quad * 8);
    acc = __builtin_amdgcn_mfma_f32_16x16x32_f16(a, wm[ksl], acc, 0, 0, 0);
  }
}

// ---- output role (8 WGs): wave-per-m16, K=40 (pad ks38-39 skipped) ----
DI void out_role(char* ws, char* smem, int nt) {
  const int tid = threadIdx.x;
  const int wave = tid >> 6, lane = tid & 63, ln16 = lane & 15, quad = lane >> 4;
  const f16* WM = (const f16*)(ws + OFF_WM);
  const f16* AM = (const f16*)(ws + OFF_AM);
  float* resb = (float*)(ws + OFF_RES);
  int* sl = (int*)(ws + OFF_FLG);
  f16* stg = (f16*)smem;                  // 34816
  float* bmL = (float*)(smem + 34816);    // 64
  int* doom = (int*)(smem + 59384);
  f16x8 wm[38];
#pragma unroll
  for (int i = 0; i < 38; ++i)
    wm[i] = *(const f16x8*)(WM + (size_t)(nt * 16 + ln16) * PM + i * 32 + quad * 8);
  if (tid < 16) bmL[tid] = ((const float*)(ws + OFF_BM))[nt * 16 + tid];
  if (tid == 0) *doom = 0;
  __syncthreads();

  for (int t = 0; t < Tn; ++t) {
    waitR(sl, doom, SB_L1, 25, t, SB_L2, 25, t, SB_L3, 25, t, 0, 0, 0);
    const f16* Ap = AM + (size_t)(t & 3) * 64 * PM;
    f32x4 acc = f32x4{0.f, 0.f, 0.f, 0.f};
    out_chunk<8>(Ap + 0 * 32, wm + 0, stg, tid, wave, quad, ln16, acc);
    out_chunk<8>(Ap + 8 * 32, wm + 8, stg, tid, wave, quad, ln16, acc);
    out_chunk<8>(Ap + 16 * 32, wm + 16, stg, tid, wave, quad, ln16, acc);
    out_chunk<8>(Ap + 24 * 32, wm + 24, stg, tid, wave, quad, ln16, acc);
    out_chunk<6>(Ap + 32 * 32, wm + 32, stg, tid, wave, quad, ln16, acc);
#pragma unroll
    for (int e = 0; e < 4; ++e) {  // C-layout: col=lane&15, row=quad*4+e
      const int m = wave * 16 + quad * 4 + e;
      resb[((size_t)t * 64 + m) * 128 + nt * 16 + ln16] = acc[e] + bmL[ln16];
    }
    arriveS(sl, SB_OUT + nt, t);
  }
}

__global__ void __launch_bounds__(256, 1) coop_kernel(char* ws, const float* x, const float* Ww) {
  __shared__ char smem[59392];
  const int id = (int)blockIdx.x;
  if (id < 25) l1_role(ws, smem, id, x, Ww);
  else if (id < 50) l2_role(ws, smem, id - 25, x);
  else if (id < 75) l3_role(ws, smem, id - 50, x);
  else if (id < 91) att_role(ws, smem, id - 75);
  else out_role(ws, smem, id - 91);
}

// ---- init: f16 weight layouts, zero A-buffers, slots, teb ----
__global__ void init_build(char* ws, const int* tok, const float* emb,
                           const float* Wih1, const float* Whh1, const float* bih1, const float* bhh1,
                           const float* Wih2, const float* Whh2, const float* bih2, const float* bhh2,
                           const float* Wih3, const float* Whh3, const float* bih3, const float* bhh3,
                           const float* bw, const float* Wm, const float* bm) {
  const int blk = (int)blockIdx.x, tid = (int)threadIdx.x;
  if (blk < 1600) {
    const int j = blk;
    f16* W1 = (f16*)(ws + OFF_W1) + (size_t)j * P1;
    f16* W2 = (f16*)(ws + OFF_W2) + (size_t)j * P2;
    f16* W3 = (f16*)(ws + OFF_W3) + (size_t)j * P2;
    for (int c = tid; c < P1; c += 256) {
      float v = 0.f;
      if (c < 64) v = Wih1[(size_t)j * 67 + 3 + c];
      else if (c < 464) v = Whh1[(size_t)j * 400 + c - 64];
      else if (c < 467) v = Wih1[(size_t)j * 67 + c - 464];
      W1[c] = (f16)v;
    }
    for (int c = tid; c < P2; c += 256) {
      float v2 = 0.f, v3 = 0.f;
      if (c < 64) { v2 = Wih2[(size_t)j * 467 + 403 + c]; v3 = Wih3[(size_t)j * 467 + 403 + c]; }
      else if (c < 464) { v2 = Wih2[(size_t)j * 467 + 3 + c - 64]; v3 = Wih3[(size_t)j * 467 + 3 + c - 64]; }
      else if (c < 467) { v2 = Wih2[(size_t)j * 467 + c - 464]; v3 = Wih3[(size_t)j * 467 + c - 464]; }
      else if (c >= 480 && c < 880) { v2 = Whh2[(size_t)j * 400 + c - 480]; v3 = Whh3[(size_t)j * 400 + c - 480]; }
      W2[c] = (f16)v2;
      W3[c] = (f16)v3;
    }
  } else if (blk < 1728) {
    const int r = blk - 1600;
    f16* WMp = (f16*)(ws + OFF_WM) + (size_t)r * PM;
    for (int c = tid; c < PM; c += 256) {
      const float v = (r < 121 && c < 1200) ? Wm[(size_t)r * 1200 + c] : 0.f;
      WMp[c] = (f16)v;
    }
  } else if (blk == 1728) {
    float* bs1 = (float*)(ws + OFF_BS1);
    float* bs2 = (float*)(ws + OFF_BS2);
    float* bs3 = (float*)(ws + OFF_BS3);
    for (int i = tid; i < 1600; i += 256) {
      bs1[i] = bih1[i] + bhh1[i];
      bs2[i] = bih2[i] + bhh2[i];
      bs3[i] = bih3[i] + bhh3[i];
    }
    float* bwp = (float*)(ws + OFF_BW);
    if (tid < 32) bwp[tid] = (tid < 30) ? bw[tid] : 0.f;
    float* bmp = (float*)(ws + OFF_BM);
    if (tid < 128) bmp[tid] = (tid < 121) ? bm[tid] : 0.f;
  } else if (blk == 1729) {
    int* fl = (int*)(ws + OFF_FLG);
    for (int i = tid; i < NSLOT; i += 256) fl[i * 32] = -1;  // t<0 presets, 1 slot/line
  } else if (blk < 1762) {
    unsigned* az = (unsigned*)(ws + OFF_A1);  // A1,A2,A3,AM contiguous
    const int n = (int)((SZ_A1 + 2 * SZ_A2 + SZ_AM) / 4);
    for (int i = (blk - 1730) * 256 + tid; i < n; i += 32 * 256) az[i] = 0u;
  } else {
    f16* tebp = (f16*)(ws + OFF_TEB);
    const int n = 64 * 96 * 64;
    for (int i = (blk - 1762) * 256 + tid; i < n; i += 128 * 256) {
      const int b = i / (96 * 64);
      const int rem = i % (96 * 64);
      const int u = rem >> 6, d = rem & 63;
      const int tk = tok[b * 96 + u];
      tebp[i] = (f16)emb[(size_t)tk * 64 + d];
    }
  }
}

// ---- epilogue: res -> (eos, softmax pi, mu, sigma, rho) ----
__global__ void postproc(const char* ws, float* out) {
  __shared__ float r[50 * 128];
  __shared__ float mx[50], dn[50];
  const float* resb = (const float*)(ws + OFF_RES);
  const int tid = (int)threadIdx.x;
  const int b = (int)blockIdx.x >> 4;
  const int t0 = ((int)blockIdx.x & 15) * 50;
  for (int idx = tid; idx < 50 * 128; idx += 256) {
    const int tt = idx >> 7, c = idx & 127;
    r[idx] = resb[((size_t)(t0 + tt) * 64 + b) * 128 + c];
  }
  __syncthreads();
  if (tid < 50) {
    float m = -1e30f;
    for (int k = 0; k < 20; ++k) m = fmaxf(m, r[tid * 128 + 1 + k]);
    float s = 0.f;
    for (int k = 0; k < 20; ++k) s += expf(r[tid * 128 + 1 + k] - m);
    mx[tid] = m;
    dn[tid] = 1.f / s;
  }
  __syncthreads();
  for (int idx = tid; idx < 50; idx += 256)
    out[O_EOS + (size_t)b * Tn + t0 + idx] = r[idx * 128];
  for (int idx = tid; idx < 50 * 20; idx += 256) {
    const int tt = idx / 20, k = idx % 20;
    const size_t o = ((size_t)b * Tn + t0 + tt) * 20 + k;
    const float* rr = &r[tt * 128];
    out[O_PI + o] = expf(rr[1 + k] - mx[tt]) * dn[tt];
    out[O_MUX + o] = rr[21 + k];
    out[O_MUY + o] = rr[41 + k];
    out[O_SX + o] = expf(rr[61 + k]) + 1e-6f;
    out[O_SY + o] = expf(rr[81 + k]) + 1e-6f;
    out[O_RHO + o] = tanhf(rr[101 + k]) * 0.999f;
  }
}

extern "C" void kernel_launch(void* const* d_in, const int* in_sizes, int n_in,
                              void* d_out, int out_size, void* d_ws, size_t ws_size,
                              hipStream_t stream) {
  const float* x = (const float*)d_in[0];
  const int* tok = (const int*)d_in[1];
  const float* emb = (const float*)d_in[2];
  const float* Wih1 = (const float*)d_in[3];
  const float* Whh1 = (const float*)d_in[4];
  const float* bih1 = (const float*)d_in[5];
  const float* bhh1 = (const float*)d_in[6];
  const float* Wih2 = (const float*)d_in[7];
  const float* Whh2 = (const float*)d_in[8];
  const float* bih2 = (const float*)d_in[9];
  const float* bhh2 = (const float*)d_in[10];
  const float* Wih3 = (const float*)d_in[11];
  const float* Whh3 = (const float*)d_in[12];
  const float* bih3 = (const float*)d_in[13];
  const float* bhh3 = (const float*)d_in[14];
  const float* Ww = (const float*)d_in[15];
  const float* bw = (const float*)d_in[16];
  const float* Wm = (const float*)d_in[17];
  const float* bm = (const float*)d_in[18];
  char* ws = (char*)d_ws;
  float* out = (float*)d_out;

  hipLaunchKernelGGL(init_build, dim3(1890), dim3(256), 0, stream,
                     ws, tok, emb, Wih1, Whh1, bih1, bhh1, Wih2, Whh2, bih2, bhh2,
                     Wih3, Whh3, bih3, bhh3, bw, Wm, bm);

  hipLaunchKernelGGL(coop_kernel, dim3(NWG), dim3(256), 0, stream, ws, x, Ww);

  hipLaunchKernelGGL(postproc, dim3(1024), dim3(256), 0, stream, ws, out);
}